// Round 3
// baseline (20939.064 us; speedup 1.0000x reference)
//
#include <hip/hip_runtime.h>

#define LSEQ 50
#define BATCH 256
#define DIN 256
#define LAT 512
#define HID 1024
#define ROWSTRIDE 257  // D_IN + 1 (dt channel)
#define NBLK 256

typedef __attribute__((ext_vector_type(8))) short s16x8;
typedef __attribute__((ext_vector_type(4))) float f32x4;
using u16 = unsigned short;

__device__ __forceinline__ u16 bfhi(float v) {
  union { float f; unsigned u; } a; a.f = v;
  return (u16)((a.u + 0x7FFFu + ((a.u >> 16) & 1u)) >> 16);
}
__device__ __forceinline__ void split2(float v, u16& h, u16& l) {
  u16 hu = bfhi(v);
  union { unsigned u; float f; } hf; hf.u = ((unsigned)hu) << 16;
  h = hu; l = bfhi(v - hf.f);
}
__device__ __forceinline__ float p2f(u16 h, u16 l) {
  union { unsigned u; float f; } a, b;
  a.u = ((unsigned)h) << 16; b.u = ((unsigned)l) << 16;
  return a.f + b.f;
}
__device__ __forceinline__ float sigmoidf_(float x) { return 1.f / (1.f + __expf(-x)); }
__device__ __forceinline__ f32x4 mfma16(s16x8 a, s16x8 b, f32x4 c) {
  return __builtin_amdgcn_mfma_f32_16x16x32_bf16(a, b, c, 0, 0, 0);
}
__device__ __forceinline__ ushort4 ldu4(const u16* p) { return *(const ushort4*)p; }
__device__ __forceinline__ void stu4(u16* p, ushort4 v) { *(ushort4*)p = v; }

// ---------- manual grid barrier (regular launch, graph-capture-safe) ----------
// bar[0] = arrive count, bar[1] = generation. Zeroed by init_k each invocation.
__device__ __forceinline__ void grid_barrier(unsigned* bar) {
  __syncthreads();
  if (threadIdx.x == 0) {
    __threadfence();  // release: all prior global writes visible at device scope
    unsigned* cnt = bar;
    unsigned* gen = bar + 1;
    unsigned g = __hip_atomic_load(gen, __ATOMIC_RELAXED, __HIP_MEMORY_SCOPE_AGENT);
    unsigned prev = __hip_atomic_fetch_add(cnt, 1u, __ATOMIC_ACQ_REL, __HIP_MEMORY_SCOPE_AGENT);
    if (prev == NBLK - 1u) {
      __hip_atomic_store(cnt, 0u, __ATOMIC_RELAXED, __HIP_MEMORY_SCOPE_AGENT);
      __hip_atomic_fetch_add(gen, 1u, __ATOMIC_RELEASE, __HIP_MEMORY_SCOPE_AGENT);
    } else {
      while (__hip_atomic_load(gen, __ATOMIC_ACQUIRE, __HIP_MEMORY_SCOPE_AGENT) == g) {
        __builtin_amdgcn_s_sleep(1);
      }
    }
    __threadfence();  // acquire: invalidate caches for subsequent reads
  }
  __syncthreads();
}

// ---------- preprocessing (round-0 verbatim) ----------
__global__ __launch_bounds__(256) void tsplit_k(const float* __restrict__ W,
    u16* __restrict__ Thi, u16* __restrict__ Tlo, int K, int N)
{
  __shared__ unsigned Ts[32][33];
  const int bk = blockIdx.x * 32, bn = blockIdx.y * 32;
  const int t = threadIdx.x;
  const int n_l = t & 31, k_l4 = (t >> 5) * 4;
  #pragma unroll
  for (int i = 0; i < 4; i++) {
    float v = W[(size_t)(bk + k_l4 + i) * N + bn + n_l];
    u16 h, l; split2(v, h, l);
    Ts[k_l4 + i][n_l] = ((unsigned)h << 16) | l;
  }
  __syncthreads();
  const int k_l = t & 31, n_l2 = t >> 5;
  #pragma unroll
  for (int i = 0; i < 4; i++) {
    int nn = n_l2 + 8 * i;
    unsigned u = Ts[k_l][nn];
    size_t o = (size_t)(bn + nn) * K + bk + k_l;
    Thi[o] = (u16)(u >> 16);
    Tlo[o] = (u16)(u & 0xFFFFu);
  }
}

__global__ __launch_bounds__(256) void esplit_k(const float* __restrict__ W,
    u16* __restrict__ Phi, u16* __restrict__ Plo)
{
  size_t i4 = ((size_t)blockIdx.x * 256 + threadIdx.x) * 4;
  float4 v = *(const float4*)&W[i4];
  u16 h[4], l[4];
  split2(v.x, h[0], l[0]); split2(v.y, h[1], l[1]);
  split2(v.z, h[2], l[2]); split2(v.w, h[3], l[3]);
  *(ushort4*)&Phi[i4] = make_ushort4(h[0], h[1], h[2], h[3]);
  *(ushort4*)&Plo[i4] = make_ushort4(l[0], l[1], l[2], l[3]);
}

__global__ __launch_bounds__(256) void init_k(u16* __restrict__ c0h, u16* __restrict__ c0l,
                                              unsigned* __restrict__ bar)
{
  size_t i4 = ((size_t)blockIdx.x * 256 + threadIdx.x) * 4;
  *(ushort4*)&c0h[i4] = make_ushort4(0, 0, 0, 0);
  *(ushort4*)&c0l[i4] = make_ushort4(0, 0, 0, 0);
  if (blockIdx.x == 0 && threadIdx.x == 0) { bar[0] = 0u; bar[1] = 0u; }
}

// ---------- double-buffered split-bf16 GEMM phase (round-0 verbatim) ----------
// EPI 1: O planes = split(tanh(acc + bias))
// EPI 2: y = p2f(O planes) + (acc + bias)*dt/3; O planes = split(y)
template<int EPI>
__device__ __forceinline__ void gemm_phase(
    u16* Sah, u16* Sal, int sA, u16* Sbh, u16* Sbl, int sB,
    const u16* __restrict__ Ahi, const u16* __restrict__ Alo, int ldA, int m0,
    const u16* __restrict__ Bhi, const u16* __restrict__ Blo, int ldB, int n0,
    int K, const float* __restrict__ bias,
    u16* __restrict__ Ohi, u16* __restrict__ Olo,
    const float* __restrict__ data, int t, int tid)
{
  const int lane = tid & 63, wave = tid >> 6;
  const int wm = (wave >> 1) << 4, wn = (wave & 1) << 4;
  const int lr = lane & 15, lq = lane >> 4;
  const int srow = tid >> 3, sk4 = (tid & 7) << 2;
  const int sidx = srow * 40 + sk4;
  f32x4 acc = {0.f, 0.f, 0.f, 0.f};
  {
    size_t oa = (size_t)(m0 + srow) * ldA + sk4;
    size_t ob = (size_t)(n0 + srow) * ldB + sk4;
    stu4(&Sah[sidx], ldu4(&Ahi[oa])); stu4(&Sal[sidx], ldu4(&Alo[oa]));
    stu4(&Sbh[sidx], ldu4(&Bhi[ob])); stu4(&Sbl[sidx], ldu4(&Blo[ob]));
  }
  __syncthreads();
  const int niter = K >> 5;
  for (int it = 0; it < niter; ++it) {
    const int db = it & 1, nb = db ^ 1;
    const bool pf = (it + 1 < niter);
    ushort4 nah, nal, nbh, nbl;
    if (pf) {
      const int k0 = (it + 1) << 5;
      size_t oa = (size_t)(m0 + srow) * ldA + k0 + sk4;
      size_t ob = (size_t)(n0 + srow) * ldB + k0 + sk4;
      nah = ldu4(&Ahi[oa]); nal = ldu4(&Alo[oa]);
      nbh = ldu4(&Bhi[ob]); nbl = ldu4(&Blo[ob]);
    }
    const int fa = db * sA + (wm + lr) * 40 + lq * 8;
    const int fb = db * sB + (wn + lr) * 40 + lq * 8;
    s16x8 ah = *(const s16x8*)&Sah[fa];
    s16x8 al = *(const s16x8*)&Sal[fa];
    s16x8 bh = *(const s16x8*)&Sbh[fb];
    s16x8 bl = *(const s16x8*)&Sbl[fb];
    acc = mfma16(ah, bh, acc);
    acc = mfma16(ah, bl, acc);
    acc = mfma16(al, bh, acc);
    if (pf) {
      stu4(&Sah[nb * sA + sidx], nah); stu4(&Sal[nb * sA + sidx], nal);
      stu4(&Sbh[nb * sB + sidx], nbh); stu4(&Sbl[nb * sB + sidx], nbl);
    }
    __syncthreads();
  }
  #pragma unroll
  for (int r = 0; r < 4; ++r) {
    const int row = m0 + wm + lq * 4 + r;
    const int col = n0 + wn + lr;
    float v = acc[r] + bias[col];
    size_t o = (size_t)row * HID + col;
    if (EPI == 1) {
      float h1 = tanhf(v);
      u16 h, l; split2(h1, h, l);
      Ohi[o] = h; Olo[o] = l;
    } else {
      float dt3 = data[(size_t)(t * BATCH + row) * ROWSTRIDE + DIN] * (1.f / 3.f);
      float y = p2f(Ohi[o], Olo[o]) + v * dt3;
      u16 h, l; split2(y, h, l);
      Ohi[o] = h; Olo[o] = l;
    }
  }
}

// ---------- fused GRU phase (round-0 gruf_k body as device function) ----------
template<bool PLANES>
__device__ __forceinline__ void gru_phase(
    u16* pool,
    const u16* __restrict__ chi, const u16* __restrict__ clo,
    const float* __restrict__ whh, const u16* __restrict__ whhh, const u16* __restrict__ whhl,
    const float* __restrict__ wih, const u16* __restrict__ wihh, const u16* __restrict__ wihl,
    const float* __restrict__ bih, const float* __restrict__ bhh,
    const float* __restrict__ data, int t,
    u16* __restrict__ nhi, u16* __restrict__ nlo,
    float* __restrict__ out, int b, int tid)
{
  u16* sAh = pool;            // 2*1280
  u16* sAl = pool + 2560;     // 2*1280
  u16* sBh = pool + 5120;     // 2*3840
  u16* sBl = pool + 12800;    // 2*3840
  const int g0 = (b & 31) << 5, m0 = (b >> 5) << 5;
  const int lane = tid & 63, wave = tid >> 6;
  const int wm = (wave >> 1) << 4, wn = (wave & 1) << 4;
  const int lr = lane & 15, lq = lane >> 4;
  const int srow = tid >> 3, sk4 = (tid & 7) << 2;
  const int sidx = srow * 40 + sk4;

  f32x4 aR = {0,0,0,0}, aZ = {0,0,0,0}, aNh = {0,0,0,0}, aNi = {0,0,0,0};
  // phase 0 preload (K-tile 0)
  {
    size_t oa = (size_t)(m0 + srow) * HID + sk4;
    stu4(&sAh[sidx], ldu4(&chi[oa])); stu4(&sAl[sidx], ldu4(&clo[oa]));
    #pragma unroll
    for (int g = 0; g < 3; ++g) {
      const size_t rrow = (size_t)(g * 1024 + g0 + srow);
      if (PLANES) {
        size_t ob = rrow * 1024 + sk4;
        stu4(&sBh[g * 1280 + sidx], ldu4(&whhh[ob]));
        stu4(&sBl[g * 1280 + sidx], ldu4(&whhl[ob]));
      } else {
        float4 w4 = *(const float4*)&whh[rrow * 1024 + sk4];
        u16 h0,l0,h1,l1,h2,l2,h3,l3;
        split2(w4.x,h0,l0); split2(w4.y,h1,l1); split2(w4.z,h2,l2); split2(w4.w,h3,l3);
        stu4(&sBh[g * 1280 + sidx], make_ushort4(h0,h1,h2,h3));
        stu4(&sBl[g * 1280 + sidx], make_ushort4(l0,l1,l2,l3));
      }
    }
  }
  __syncthreads();
  for (int it = 0; it < 32; ++it) {
    const int db = it & 1, nb = db ^ 1;
    const bool pf = (it + 1 < 32);
    ushort4 nah, nal, nb0h, nb0l, nb1h, nb1l, nb2h, nb2l;
    if (pf) {
      const int k0 = (it + 1) << 5;
      size_t oa = (size_t)(m0 + srow) * HID + k0 + sk4;
      nah = ldu4(&chi[oa]); nal = ldu4(&clo[oa]);
      if (PLANES) {
        size_t r0 = (size_t)(0 * 1024 + g0 + srow) * 1024 + k0 + sk4;
        size_t r1 = (size_t)(1 * 1024 + g0 + srow) * 1024 + k0 + sk4;
        size_t r2 = (size_t)(2 * 1024 + g0 + srow) * 1024 + k0 + sk4;
        nb0h = ldu4(&whhh[r0]); nb0l = ldu4(&whhl[r0]);
        nb1h = ldu4(&whhh[r1]); nb1l = ldu4(&whhl[r1]);
        nb2h = ldu4(&whhh[r2]); nb2l = ldu4(&whhl[r2]);
      } else {
        #pragma unroll
        for (int g = 0; g < 3; ++g) {
          float4 w4 = *(const float4*)&whh[(size_t)(g * 1024 + g0 + srow) * 1024 + k0 + sk4];
          u16 h0,l0,h1,l1,h2,l2,h3,l3;
          split2(w4.x,h0,l0); split2(w4.y,h1,l1); split2(w4.z,h2,l2); split2(w4.w,h3,l3);
          ushort4 hh = make_ushort4(h0,h1,h2,h3), ll = make_ushort4(l0,l1,l2,l3);
          if (g == 0) { nb0h = hh; nb0l = ll; }
          else if (g == 1) { nb1h = hh; nb1l = ll; }
          else { nb2h = hh; nb2l = ll; }
        }
      }
    }
    const int fa = db * 1280 + (wm + lr) * 40 + lq * 8;
    s16x8 ah = *(const s16x8*)&sAh[fa];
    s16x8 al = *(const s16x8*)&sAl[fa];
    #pragma unroll
    for (int g = 0; g < 3; ++g) {
      const int fb = db * 3840 + g * 1280 + (wn + lr) * 40 + lq * 8;
      s16x8 bh = *(const s16x8*)&sBh[fb];
      s16x8 bl = *(const s16x8*)&sBl[fb];
      f32x4 c = (g == 0) ? aR : (g == 1) ? aZ : aNh;
      c = mfma16(ah, bh, c); c = mfma16(ah, bl, c); c = mfma16(al, bh, c);
      if (g == 0) aR = c; else if (g == 1) aZ = c; else aNh = c;
    }
    if (pf) {
      stu4(&sAh[nb * 1280 + sidx], nah); stu4(&sAl[nb * 1280 + sidx], nal);
      stu4(&sBh[nb * 3840 + 0 * 1280 + sidx], nb0h); stu4(&sBl[nb * 3840 + 0 * 1280 + sidx], nb0l);
      stu4(&sBh[nb * 3840 + 1 * 1280 + sidx], nb1h); stu4(&sBl[nb * 3840 + 1 * 1280 + sidx], nb1l);
      stu4(&sBh[nb * 3840 + 2 * 1280 + sidx], nb2h); stu4(&sBl[nb * 3840 + 2 * 1280 + sidx], nb2l);
    }
    __syncthreads();
  }
  // phase 1: gi (x_t split on the fly), K = 256
  {
    const float* xp = &data[(size_t)(t * BATCH + m0 + srow) * ROWSTRIDE + sk4];
    u16 xh[4], xl[4];
    #pragma unroll
    for (int i = 0; i < 4; i++) split2(xp[i], xh[i], xl[i]);
    stu4(&sAh[sidx], make_ushort4(xh[0], xh[1], xh[2], xh[3]));
    stu4(&sAl[sidx], make_ushort4(xl[0], xl[1], xl[2], xl[3]));
    #pragma unroll
    for (int g = 0; g < 3; ++g) {
      const size_t rrow = (size_t)(g * 1024 + g0 + srow);
      if (PLANES) {
        size_t ob = rrow * 256 + sk4;
        stu4(&sBh[g * 1280 + sidx], ldu4(&wihh[ob]));
        stu4(&sBl[g * 1280 + sidx], ldu4(&wihl[ob]));
      } else {
        float4 w4 = *(const float4*)&wih[rrow * 256 + sk4];
        u16 h0,l0,h1,l1,h2,l2,h3,l3;
        split2(w4.x,h0,l0); split2(w4.y,h1,l1); split2(w4.z,h2,l2); split2(w4.w,h3,l3);
        stu4(&sBh[g * 1280 + sidx], make_ushort4(h0,h1,h2,h3));
        stu4(&sBl[g * 1280 + sidx], make_ushort4(l0,l1,l2,l3));
      }
    }
  }
  __syncthreads();
  for (int it = 0; it < 8; ++it) {
    const int db = it & 1, nb = db ^ 1;
    const bool pf = (it + 1 < 8);
    ushort4 nah, nal, nb0h, nb0l, nb1h, nb1l, nb2h, nb2l;
    if (pf) {
      const int k0 = (it + 1) << 5;
      const float* xp = &data[(size_t)(t * BATCH + m0 + srow) * ROWSTRIDE + k0 + sk4];
      u16 xh[4], xl[4];
      #pragma unroll
      for (int i = 0; i < 4; i++) split2(xp[i], xh[i], xl[i]);
      nah = make_ushort4(xh[0], xh[1], xh[2], xh[3]);
      nal = make_ushort4(xl[0], xl[1], xl[2], xl[3]);
      if (PLANES) {
        size_t r0 = (size_t)(0 * 1024 + g0 + srow) * 256 + k0 + sk4;
        size_t r1 = (size_t)(1 * 1024 + g0 + srow) * 256 + k0 + sk4;
        size_t r2 = (size_t)(2 * 1024 + g0 + srow) * 256 + k0 + sk4;
        nb0h = ldu4(&wihh[r0]); nb0l = ldu4(&wihl[r0]);
        nb1h = ldu4(&wihh[r1]); nb1l = ldu4(&wihl[r1]);
        nb2h = ldu4(&wihh[r2]); nb2l = ldu4(&wihl[r2]);
      } else {
        #pragma unroll
        for (int g = 0; g < 3; ++g) {
          float4 w4 = *(const float4*)&wih[(size_t)(g * 1024 + g0 + srow) * 256 + k0 + sk4];
          u16 h0,l0,h1,l1,h2,l2,h3,l3;
          split2(w4.x,h0,l0); split2(w4.y,h1,l1); split2(w4.z,h2,l2); split2(w4.w,h3,l3);
          ushort4 hh = make_ushort4(h0,h1,h2,h3), ll = make_ushort4(l0,l1,l2,l3);
          if (g == 0) { nb0h = hh; nb0l = ll; }
          else if (g == 1) { nb1h = hh; nb1l = ll; }
          else { nb2h = hh; nb2l = ll; }
        }
      }
    }
    const int fa = db * 1280 + (wm + lr) * 40 + lq * 8;
    s16x8 ah = *(const s16x8*)&sAh[fa];
    s16x8 al = *(const s16x8*)&sAl[fa];
    #pragma unroll
    for (int g = 0; g < 3; ++g) {
      const int fb = db * 3840 + g * 1280 + (wn + lr) * 40 + lq * 8;
      s16x8 bh = *(const s16x8*)&sBh[fb];
      s16x8 bl = *(const s16x8*)&sBl[fb];
      f32x4 c = (g == 0) ? aR : (g == 1) ? aZ : aNi;
      c = mfma16(ah, bh, c); c = mfma16(ah, bl, c); c = mfma16(al, bh, c);
      if (g == 0) aR = c; else if (g == 1) aZ = c; else aNi = c;
    }
    if (pf) {
      stu4(&sAh[nb * 1280 + sidx], nah); stu4(&sAl[nb * 1280 + sidx], nal);
      stu4(&sBh[nb * 3840 + 0 * 1280 + sidx], nb0h); stu4(&sBl[nb * 3840 + 0 * 1280 + sidx], nb0l);
      stu4(&sBh[nb * 3840 + 1 * 1280 + sidx], nb1h); stu4(&sBl[nb * 3840 + 1 * 1280 + sidx], nb1l);
      stu4(&sBh[nb * 3840 + 2 * 1280 + sidx], nb2h); stu4(&sBl[nb * 3840 + 2 * 1280 + sidx], nb2l);
    }
    __syncthreads();
  }
  // epilogue: pointwise GRU + outputs + next state
  #pragma unroll
  for (int r = 0; r < 4; ++r) {
    const int row = m0 + wm + lq * 4 + r;
    const int jg = g0 + wn + lr;
    float rr = sigmoidf_(aR[r] + bih[jg] + bhh[jg]);
    float zz = sigmoidf_(aZ[r] + bih[1024 + jg] + bhh[1024 + jg]);
    float nn = tanhf(aNi[r] + bih[2048 + jg] + rr * (aNh[r] + bhh[2048 + jg]));
    size_t oh = (size_t)row * HID + jg;
    float hv = p2f(chi[oh], clo[oh]);
    float val = (1.f - zz) * nn + zz * hv;
    out[(size_t)LSEQ * BATCH * LAT + oh] = val;        // output 1 (new_h)
    if (jg < LAT) {
      out[((size_t)t * BATCH + row) * LAT + jg] = val; // output 0
      u16 h, l; split2(val, h, l);
      nhi[oh] = h; nhi[oh + LAT] = h;
      nlo[oh] = l; nlo[oh + LAT] = l;
    }
  }
}

// ---------- one persistent kernel for the whole recurrence ----------
template<bool PLANES>
__global__ __launch_bounds__(256, 1) void fused_seq_k(
    const u16* __restrict__ w1h, const u16* __restrict__ w1l,
    const u16* __restrict__ w2h, const u16* __restrict__ w2l,
    const float* __restrict__ b1, const float* __restrict__ b2,
    u16* __restrict__ c0h, u16* __restrict__ c0l,
    u16* __restrict__ c1h, u16* __restrict__ c1l,
    u16* __restrict__ h1h, u16* __restrict__ h1l,
    const float* __restrict__ whh, const u16* __restrict__ whhh, const u16* __restrict__ whhl,
    const float* __restrict__ wih, const u16* __restrict__ wihh, const u16* __restrict__ wihl,
    const float* __restrict__ bih, const float* __restrict__ bhh,
    const float* __restrict__ data, float* __restrict__ out,
    unsigned* __restrict__ bar)
{
  __shared__ u16 pool[20480];   // 40 KB, carved per phase
  const int b = blockIdx.x;
  const int tid = threadIdx.x;

  for (int t = 0; t < LSEQ; ++t) {
    u16* chi = (t & 1) ? c1h : c0h;
    u16* clo = (t & 1) ? c1l : c0l;
    u16* nhi = (t & 1) ? c0h : c1h;
    u16* nlo = (t & 1) ? c0l : c1l;
    for (int s = 0; s < 3; ++s) {
      {  // mlp1: 256 tiles of 32x32 -> h1 = tanh(y @ w1 + b1)
        const int n0 = (b & 31) << 5, m0 = (b >> 5) << 5;
        gemm_phase<1>(pool, pool + 2560, 1280, pool + 5120, pool + 7680, 1280,
                      chi, clo, HID, m0, w1h, w1l, 512, n0, 512,
                      b1, h1h, h1l, data, t, tid);
      }
      grid_barrier(bar);
      if (b < 128) {  // mlp2: 128 tiles of 32x32 -> y += (h1 @ w2 + b2)*dt/3
        const int n0 = (b & 15) << 5, m0 = (b >> 4) << 5;
        gemm_phase<2>(pool, pool + 2560, 1280, pool + 5120, pool + 7680, 1280,
                      h1h, h1l, HID, m0, w2h, w2l, 1024, n0, 1024,
                      b2, chi, clo, data, t, tid);
      }
      grid_barrier(bar);
    }
    gru_phase<PLANES>(pool, chi, clo, whh, whhh, whhl, wih, wihh, wihl,
                      bih, bhh, data, t, nhi, nlo, out, b, tid);
    if (t + 1 < LSEQ) grid_barrier(bar);
  }
}

extern "C" void kernel_launch(void* const* d_in, const int* in_sizes, int n_in,
                              void* d_out, int out_size, void* d_ws, size_t ws_size,
                              hipStream_t stream)
{
  const float* data = (const float*)d_in[0];
  const float* w1   = (const float*)d_in[1];
  const float* b1   = (const float*)d_in[2];
  const float* w2   = (const float*)d_in[3];
  const float* b2   = (const float*)d_in[4];
  const float* wih  = (const float*)d_in[5];
  const float* bih  = (const float*)d_in[6];
  const float* whh  = (const float*)d_in[7];
  const float* bhh  = (const float*)d_in[8];
  float* out = (float*)d_out;

  char* w = (char*)d_ws;
  auto alloc = [&](size_t bytes) { char* p = w; w += bytes; return p; };
  u16* w1h = (u16*)alloc((size_t)512 * 1024 * 2);   // [1024 n][512 k] planes
  u16* w1l = (u16*)alloc((size_t)512 * 1024 * 2);
  u16* w2h = (u16*)alloc((size_t)512 * 1024 * 2);   // [512 n][1024 k] planes
  u16* w2l = (u16*)alloc((size_t)512 * 1024 * 2);
  u16* c0h = (u16*)alloc((size_t)BATCH * HID * 2);
  u16* c0l = (u16*)alloc((size_t)BATCH * HID * 2);
  u16* c1h = (u16*)alloc((size_t)BATCH * HID * 2);
  u16* c1l = (u16*)alloc((size_t)BATCH * HID * 2);
  u16* h1h = (u16*)alloc((size_t)BATCH * HID * 2);
  u16* h1l = (u16*)alloc((size_t)BATCH * HID * 2);
  unsigned* bar = (unsigned*)alloc(256);             // barrier state (count, gen)
  size_t base = (size_t)(w - (char*)d_ws);
  size_t need_opt = base + 2 * ((size_t)3072 * 1024 * 2) + 2 * ((size_t)3072 * 256 * 2);
  bool planes = ws_size >= need_opt;
  u16 *whhh = nullptr, *whhl = nullptr, *wihh = nullptr, *wihl = nullptr;
  if (planes) {
    whhh = (u16*)alloc((size_t)3072 * 1024 * 2);
    whhl = (u16*)alloc((size_t)3072 * 1024 * 2);
    wihh = (u16*)alloc((size_t)3072 * 256 * 2);
    wihl = (u16*)alloc((size_t)3072 * 256 * 2);
  }

  tsplit_k<<<dim3(512 / 32, 1024 / 32), 256, 0, stream>>>(w1, w1h, w1l, 512, 1024);
  tsplit_k<<<dim3(1024 / 32, 512 / 32), 256, 0, stream>>>(w2, w2h, w2l, 1024, 512);
  if (planes) {
    esplit_k<<<dim3((3072 * 1024) / 1024), 256, 0, stream>>>(whh, whhh, whhl);
    esplit_k<<<dim3((3072 * 256) / 1024), 256, 0, stream>>>(wih, wihh, wihl);
  }
  init_k<<<dim3(256), 256, 0, stream>>>(c0h, c0l, bar);

  if (planes) {
    fused_seq_k<true><<<dim3(NBLK), dim3(256), 0, stream>>>(
        w1h, w1l, w2h, w2l, b1, b2, c0h, c0l, c1h, c1l, h1h, h1l,
        whh, whhh, whhl, wih, wihh, wihl, bih, bhh, data, out, bar);
  } else {
    fused_seq_k<false><<<dim3(NBLK), dim3(256), 0, stream>>>(
        w1h, w1l, w2h, w2l, b1, b2, c0h, c0l, c1h, c1l, h1h, h1l,
        whh, whhh, whhl, wih, wihh, wihl, bih, bhh, data, out, bar);
  }
}

// Round 4
// 10252.237 us; speedup vs baseline: 2.0424x; 2.0424x over previous
//
#include <hip/hip_runtime.h>

#define LSEQ 50
#define BATCH 256
#define DIN 256
#define LAT 512
#define HID 1024
#define ROWSTRIDE 257  // D_IN + 1 (dt channel)
#define NBLK 256

typedef __attribute__((ext_vector_type(8))) short s16x8;
typedef __attribute__((ext_vector_type(4))) float f32x4;
using u16 = unsigned short;

__device__ __forceinline__ u16 bfhi(float v) {
  union { float f; unsigned u; } a; a.f = v;
  return (u16)((a.u + 0x7FFFu + ((a.u >> 16) & 1u)) >> 16);
}
__device__ __forceinline__ void split2(float v, u16& h, u16& l) {
  u16 hu = bfhi(v);
  union { unsigned u; float f; } hf; hf.u = ((unsigned)hu) << 16;
  h = hu; l = bfhi(v - hf.f);
}
__device__ __forceinline__ float p2f(u16 h, u16 l) {
  union { unsigned u; float f; } a, b;
  a.u = ((unsigned)h) << 16; b.u = ((unsigned)l) << 16;
  return a.f + b.f;
}
__device__ __forceinline__ float sigmoidf_(float x) { return 1.f / (1.f + __expf(-x)); }
__device__ __forceinline__ f32x4 mfma16(s16x8 a, s16x8 b, f32x4 c) {
  return __builtin_amdgcn_mfma_f32_16x16x32_bf16(a, b, c, 0, 0, 0);
}
__device__ __forceinline__ ushort4 ldu4(const u16* p) { return *(const ushort4*)p; }
__device__ __forceinline__ void stu4(u16* p, ushort4 v) { *(ushort4*)p = v; }

// ---------- manual grid barrier: monotonic counter, relaxed poll, one fence pair ----------
// bar[0] zeroed by init_k each invocation. rnd is a per-block register target.
__device__ __forceinline__ void grid_barrier(unsigned* bar, unsigned& rnd) {
  __syncthreads();
  rnd += NBLK;
  if (threadIdx.x == 0) {
    __builtin_amdgcn_fence(__ATOMIC_RELEASE, "agent");   // make prior writes visible (L2 wb)
    __hip_atomic_fetch_add(bar, 1u, __ATOMIC_RELAXED, __HIP_MEMORY_SCOPE_AGENT);
    while (__hip_atomic_load(bar, __ATOMIC_RELAXED, __HIP_MEMORY_SCOPE_AGENT) < rnd) {
      __builtin_amdgcn_s_sleep(2);                       // relaxed poll: NO per-iter L2 inv
    }
    __builtin_amdgcn_fence(__ATOMIC_ACQUIRE, "agent");   // one L2 inv before consuming
  }
  __syncthreads();
}

// ---------- preprocessing (round-0 verbatim) ----------
__global__ __launch_bounds__(256) void tsplit_k(const float* __restrict__ W,
    u16* __restrict__ Thi, u16* __restrict__ Tlo, int K, int N)
{
  __shared__ unsigned Ts[32][33];
  const int bk = blockIdx.x * 32, bn = blockIdx.y * 32;
  const int t = threadIdx.x;
  const int n_l = t & 31, k_l4 = (t >> 5) * 4;
  #pragma unroll
  for (int i = 0; i < 4; i++) {
    float v = W[(size_t)(bk + k_l4 + i) * N + bn + n_l];
    u16 h, l; split2(v, h, l);
    Ts[k_l4 + i][n_l] = ((unsigned)h << 16) | l;
  }
  __syncthreads();
  const int k_l = t & 31, n_l2 = t >> 5;
  #pragma unroll
  for (int i = 0; i < 4; i++) {
    int nn = n_l2 + 8 * i;
    unsigned u = Ts[k_l][nn];
    size_t o = (size_t)(bn + nn) * K + bk + k_l;
    Thi[o] = (u16)(u >> 16);
    Tlo[o] = (u16)(u & 0xFFFFu);
  }
}

__global__ __launch_bounds__(256) void esplit_k(const float* __restrict__ W,
    u16* __restrict__ Phi, u16* __restrict__ Plo)
{
  size_t i4 = ((size_t)blockIdx.x * 256 + threadIdx.x) * 4;
  float4 v = *(const float4*)&W[i4];
  u16 h[4], l[4];
  split2(v.x, h[0], l[0]); split2(v.y, h[1], l[1]);
  split2(v.z, h[2], l[2]); split2(v.w, h[3], l[3]);
  *(ushort4*)&Phi[i4] = make_ushort4(h[0], h[1], h[2], h[3]);
  *(ushort4*)&Plo[i4] = make_ushort4(l[0], l[1], l[2], l[3]);
}

__global__ __launch_bounds__(256) void init_k(u16* __restrict__ c0h, u16* __restrict__ c0l,
                                              unsigned* __restrict__ bar)
{
  size_t i4 = ((size_t)blockIdx.x * 256 + threadIdx.x) * 4;
  *(ushort4*)&c0h[i4] = make_ushort4(0, 0, 0, 0);
  *(ushort4*)&c0l[i4] = make_ushort4(0, 0, 0, 0);
  if (blockIdx.x == 0 && threadIdx.x == 0) { bar[0] = 0u; bar[1] = 0u; }
}

// ---------- double-buffered split-bf16 GEMM phase (round-0 verbatim) ----------
// EPI 1: O planes = split(tanh(acc + bias))
// EPI 2: y = p2f(O planes) + (acc + bias)*dt/3; O planes = split(y)
template<int EPI>
__device__ __forceinline__ void gemm_phase(
    u16* Sah, u16* Sal, int sA, u16* Sbh, u16* Sbl, int sB,
    const u16* __restrict__ Ahi, const u16* __restrict__ Alo, int ldA, int m0,
    const u16* __restrict__ Bhi, const u16* __restrict__ Blo, int ldB, int n0,
    int K, const float* __restrict__ bias,
    u16* __restrict__ Ohi, u16* __restrict__ Olo,
    const float* __restrict__ data, int t, int tid)
{
  const int lane = tid & 63, wave = tid >> 6;
  const int wm = (wave >> 1) << 4, wn = (wave & 1) << 4;
  const int lr = lane & 15, lq = lane >> 4;
  const int srow = tid >> 3, sk4 = (tid & 7) << 2;
  const int sidx = srow * 40 + sk4;
  f32x4 acc = {0.f, 0.f, 0.f, 0.f};
  {
    size_t oa = (size_t)(m0 + srow) * ldA + sk4;
    size_t ob = (size_t)(n0 + srow) * ldB + sk4;
    stu4(&Sah[sidx], ldu4(&Ahi[oa])); stu4(&Sal[sidx], ldu4(&Alo[oa]));
    stu4(&Sbh[sidx], ldu4(&Bhi[ob])); stu4(&Sbl[sidx], ldu4(&Blo[ob]));
  }
  __syncthreads();
  const int niter = K >> 5;
  for (int it = 0; it < niter; ++it) {
    const int db = it & 1, nb = db ^ 1;
    const bool pf = (it + 1 < niter);
    ushort4 nah, nal, nbh, nbl;
    if (pf) {
      const int k0 = (it + 1) << 5;
      size_t oa = (size_t)(m0 + srow) * ldA + k0 + sk4;
      size_t ob = (size_t)(n0 + srow) * ldB + k0 + sk4;
      nah = ldu4(&Ahi[oa]); nal = ldu4(&Alo[oa]);
      nbh = ldu4(&Bhi[ob]); nbl = ldu4(&Blo[ob]);
    }
    const int fa = db * sA + (wm + lr) * 40 + lq * 8;
    const int fb = db * sB + (wn + lr) * 40 + lq * 8;
    s16x8 ah = *(const s16x8*)&Sah[fa];
    s16x8 al = *(const s16x8*)&Sal[fa];
    s16x8 bh = *(const s16x8*)&Sbh[fb];
    s16x8 bl = *(const s16x8*)&Sbl[fb];
    acc = mfma16(ah, bh, acc);
    acc = mfma16(ah, bl, acc);
    acc = mfma16(al, bh, acc);
    if (pf) {
      stu4(&Sah[nb * sA + sidx], nah); stu4(&Sal[nb * sA + sidx], nal);
      stu4(&Sbh[nb * sB + sidx], nbh); stu4(&Sbl[nb * sB + sidx], nbl);
    }
    __syncthreads();
  }
  #pragma unroll
  for (int r = 0; r < 4; ++r) {
    const int row = m0 + wm + lq * 4 + r;
    const int col = n0 + wn + lr;
    float v = acc[r] + bias[col];
    size_t o = (size_t)row * HID + col;
    if (EPI == 1) {
      float h1 = tanhf(v);
      u16 h, l; split2(h1, h, l);
      Ohi[o] = h; Olo[o] = l;
    } else {
      float dt3 = data[(size_t)(t * BATCH + row) * ROWSTRIDE + DIN] * (1.f / 3.f);
      float y = p2f(Ohi[o], Olo[o]) + v * dt3;
      u16 h, l; split2(y, h, l);
      Ohi[o] = h; Olo[o] = l;
    }
  }
}

// ---------- fused GRU phase (round-0 gruf_k body as device function) ----------
template<bool PLANES>
__device__ __forceinline__ void gru_phase(
    u16* pool,
    const u16* __restrict__ chi, const u16* __restrict__ clo,
    const float* __restrict__ whh, const u16* __restrict__ whhh, const u16* __restrict__ whhl,
    const float* __restrict__ wih, const u16* __restrict__ wihh, const u16* __restrict__ wihl,
    const float* __restrict__ bih, const float* __restrict__ bhh,
    const float* __restrict__ data, int t,
    u16* __restrict__ nhi, u16* __restrict__ nlo,
    float* __restrict__ out, int b, int tid)
{
  u16* sAh = pool;            // 2*1280
  u16* sAl = pool + 2560;     // 2*1280
  u16* sBh = pool + 5120;     // 2*3840
  u16* sBl = pool + 12800;    // 2*3840
  const int g0 = (b & 31) << 5, m0 = (b >> 5) << 5;
  const int lane = tid & 63, wave = tid >> 6;
  const int wm = (wave >> 1) << 4, wn = (wave & 1) << 4;
  const int lr = lane & 15, lq = lane >> 4;
  const int srow = tid >> 3, sk4 = (tid & 7) << 2;
  const int sidx = srow * 40 + sk4;

  f32x4 aR = {0,0,0,0}, aZ = {0,0,0,0}, aNh = {0,0,0,0}, aNi = {0,0,0,0};
  // phase 0 preload (K-tile 0)
  {
    size_t oa = (size_t)(m0 + srow) * HID + sk4;
    stu4(&sAh[sidx], ldu4(&chi[oa])); stu4(&sAl[sidx], ldu4(&clo[oa]));
    #pragma unroll
    for (int g = 0; g < 3; ++g) {
      const size_t rrow = (size_t)(g * 1024 + g0 + srow);
      if (PLANES) {
        size_t ob = rrow * 1024 + sk4;
        stu4(&sBh[g * 1280 + sidx], ldu4(&whhh[ob]));
        stu4(&sBl[g * 1280 + sidx], ldu4(&whhl[ob]));
      } else {
        float4 w4 = *(const float4*)&whh[rrow * 1024 + sk4];
        u16 h0,l0,h1,l1,h2,l2,h3,l3;
        split2(w4.x,h0,l0); split2(w4.y,h1,l1); split2(w4.z,h2,l2); split2(w4.w,h3,l3);
        stu4(&sBh[g * 1280 + sidx], make_ushort4(h0,h1,h2,h3));
        stu4(&sBl[g * 1280 + sidx], make_ushort4(l0,l1,l2,l3));
      }
    }
  }
  __syncthreads();
  for (int it = 0; it < 32; ++it) {
    const int db = it & 1, nb = db ^ 1;
    const bool pf = (it + 1 < 32);
    ushort4 nah, nal, nb0h, nb0l, nb1h, nb1l, nb2h, nb2l;
    if (pf) {
      const int k0 = (it + 1) << 5;
      size_t oa = (size_t)(m0 + srow) * HID + k0 + sk4;
      nah = ldu4(&chi[oa]); nal = ldu4(&clo[oa]);
      if (PLANES) {
        size_t r0 = (size_t)(0 * 1024 + g0 + srow) * 1024 + k0 + sk4;
        size_t r1 = (size_t)(1 * 1024 + g0 + srow) * 1024 + k0 + sk4;
        size_t r2 = (size_t)(2 * 1024 + g0 + srow) * 1024 + k0 + sk4;
        nb0h = ldu4(&whhh[r0]); nb0l = ldu4(&whhl[r0]);
        nb1h = ldu4(&whhh[r1]); nb1l = ldu4(&whhl[r1]);
        nb2h = ldu4(&whhh[r2]); nb2l = ldu4(&whhl[r2]);
      } else {
        #pragma unroll
        for (int g = 0; g < 3; ++g) {
          float4 w4 = *(const float4*)&whh[(size_t)(g * 1024 + g0 + srow) * 1024 + k0 + sk4];
          u16 h0,l0,h1,l1,h2,l2,h3,l3;
          split2(w4.x,h0,l0); split2(w4.y,h1,l1); split2(w4.z,h2,l2); split2(w4.w,h3,l3);
          ushort4 hh = make_ushort4(h0,h1,h2,h3), ll = make_ushort4(l0,l1,l2,l3);
          if (g == 0) { nb0h = hh; nb0l = ll; }
          else if (g == 1) { nb1h = hh; nb1l = ll; }
          else { nb2h = hh; nb2l = ll; }
        }
      }
    }
    const int fa = db * 1280 + (wm + lr) * 40 + lq * 8;
    s16x8 ah = *(const s16x8*)&sAh[fa];
    s16x8 al = *(const s16x8*)&sAl[fa];
    #pragma unroll
    for (int g = 0; g < 3; ++g) {
      const int fb = db * 3840 + g * 1280 + (wn + lr) * 40 + lq * 8;
      s16x8 bh = *(const s16x8*)&sBh[fb];
      s16x8 bl = *(const s16x8*)&sBl[fb];
      f32x4 c = (g == 0) ? aR : (g == 1) ? aZ : aNh;
      c = mfma16(ah, bh, c); c = mfma16(ah, bl, c); c = mfma16(al, bh, c);
      if (g == 0) aR = c; else if (g == 1) aZ = c; else aNh = c;
    }
    if (pf) {
      stu4(&sAh[nb * 1280 + sidx], nah); stu4(&sAl[nb * 1280 + sidx], nal);
      stu4(&sBh[nb * 3840 + 0 * 1280 + sidx], nb0h); stu4(&sBl[nb * 3840 + 0 * 1280 + sidx], nb0l);
      stu4(&sBh[nb * 3840 + 1 * 1280 + sidx], nb1h); stu4(&sBl[nb * 3840 + 1 * 1280 + sidx], nb1l);
      stu4(&sBh[nb * 3840 + 2 * 1280 + sidx], nb2h); stu4(&sBl[nb * 3840 + 2 * 1280 + sidx], nb2l);
    }
    __syncthreads();
  }
  // phase 1: gi (x_t split on the fly), K = 256
  {
    const float* xp = &data[(size_t)(t * BATCH + m0 + srow) * ROWSTRIDE + sk4];
    u16 xh[4], xl[4];
    #pragma unroll
    for (int i = 0; i < 4; i++) split2(xp[i], xh[i], xl[i]);
    stu4(&sAh[sidx], make_ushort4(xh[0], xh[1], xh[2], xh[3]));
    stu4(&sAl[sidx], make_ushort4(xl[0], xl[1], xl[2], xl[3]));
    #pragma unroll
    for (int g = 0; g < 3; ++g) {
      const size_t rrow = (size_t)(g * 1024 + g0 + srow);
      if (PLANES) {
        size_t ob = rrow * 256 + sk4;
        stu4(&sBh[g * 1280 + sidx], ldu4(&wihh[ob]));
        stu4(&sBl[g * 1280 + sidx], ldu4(&wihl[ob]));
      } else {
        float4 w4 = *(const float4*)&wih[rrow * 256 + sk4];
        u16 h0,l0,h1,l1,h2,l2,h3,l3;
        split2(w4.x,h0,l0); split2(w4.y,h1,l1); split2(w4.z,h2,l2); split2(w4.w,h3,l3);
        stu4(&sBh[g * 1280 + sidx], make_ushort4(h0,h1,h2,h3));
        stu4(&sBl[g * 1280 + sidx], make_ushort4(l0,l1,l2,l3));
      }
    }
  }
  __syncthreads();
  for (int it = 0; it < 8; ++it) {
    const int db = it & 1, nb = db ^ 1;
    const bool pf = (it + 1 < 8);
    ushort4 nah, nal, nb0h, nb0l, nb1h, nb1l, nb2h, nb2l;
    if (pf) {
      const int k0 = (it + 1) << 5;
      const float* xp = &data[(size_t)(t * BATCH + m0 + srow) * ROWSTRIDE + k0 + sk4];
      u16 xh[4], xl[4];
      #pragma unroll
      for (int i = 0; i < 4; i++) split2(xp[i], xh[i], xl[i]);
      nah = make_ushort4(xh[0], xh[1], xh[2], xh[3]);
      nal = make_ushort4(xl[0], xl[1], xl[2], xl[3]);
      if (PLANES) {
        size_t r0 = (size_t)(0 * 1024 + g0 + srow) * 256 + k0 + sk4;
        size_t r1 = (size_t)(1 * 1024 + g0 + srow) * 256 + k0 + sk4;
        size_t r2 = (size_t)(2 * 1024 + g0 + srow) * 256 + k0 + sk4;
        nb0h = ldu4(&wihh[r0]); nb0l = ldu4(&wihl[r0]);
        nb1h = ldu4(&wihh[r1]); nb1l = ldu4(&wihl[r1]);
        nb2h = ldu4(&wihh[r2]); nb2l = ldu4(&wihl[r2]);
      } else {
        #pragma unroll
        for (int g = 0; g < 3; ++g) {
          float4 w4 = *(const float4*)&wih[(size_t)(g * 1024 + g0 + srow) * 256 + k0 + sk4];
          u16 h0,l0,h1,l1,h2,l2,h3,l3;
          split2(w4.x,h0,l0); split2(w4.y,h1,l1); split2(w4.z,h2,l2); split2(w4.w,h3,l3);
          ushort4 hh = make_ushort4(h0,h1,h2,h3), ll = make_ushort4(l0,l1,l2,l3);
          if (g == 0) { nb0h = hh; nb0l = ll; }
          else if (g == 1) { nb1h = hh; nb1l = ll; }
          else { nb2h = hh; nb2l = ll; }
        }
      }
    }
    const int fa = db * 1280 + (wm + lr) * 40 + lq * 8;
    s16x8 ah = *(const s16x8*)&sAh[fa];
    s16x8 al = *(const s16x8*)&sAl[fa];
    #pragma unroll
    for (int g = 0; g < 3; ++g) {
      const int fb = db * 3840 + g * 1280 + (wn + lr) * 40 + lq * 8;
      s16x8 bh = *(const s16x8*)&sBh[fb];
      s16x8 bl = *(const s16x8*)&sBl[fb];
      f32x4 c = (g == 0) ? aR : (g == 1) ? aZ : aNi;
      c = mfma16(ah, bh, c); c = mfma16(ah, bl, c); c = mfma16(al, bh, c);
      if (g == 0) aR = c; else if (g == 1) aZ = c; else aNi = c;
    }
    if (pf) {
      stu4(&sAh[nb * 1280 + sidx], nah); stu4(&sAl[nb * 1280 + sidx], nal);
      stu4(&sBh[nb * 3840 + 0 * 1280 + sidx], nb0h); stu4(&sBl[nb * 3840 + 0 * 1280 + sidx], nb0l);
      stu4(&sBh[nb * 3840 + 1 * 1280 + sidx], nb1h); stu4(&sBl[nb * 3840 + 1 * 1280 + sidx], nb1l);
      stu4(&sBh[nb * 3840 + 2 * 1280 + sidx], nb2h); stu4(&sBl[nb * 3840 + 2 * 1280 + sidx], nb2l);
    }
    __syncthreads();
  }
  // epilogue: pointwise GRU + outputs + next state
  #pragma unroll
  for (int r = 0; r < 4; ++r) {
    const int row = m0 + wm + lq * 4 + r;
    const int jg = g0 + wn + lr;
    float rr = sigmoidf_(aR[r] + bih[jg] + bhh[jg]);
    float zz = sigmoidf_(aZ[r] + bih[1024 + jg] + bhh[1024 + jg]);
    float nn = tanhf(aNi[r] + bih[2048 + jg] + rr * (aNh[r] + bhh[2048 + jg]));
    size_t oh = (size_t)row * HID + jg;
    float hv = p2f(chi[oh], clo[oh]);
    float val = (1.f - zz) * nn + zz * hv;
    out[(size_t)LSEQ * BATCH * LAT + oh] = val;        // output 1 (new_h)
    if (jg < LAT) {
      out[((size_t)t * BATCH + row) * LAT + jg] = val; // output 0
      u16 h, l; split2(val, h, l);
      nhi[oh] = h; nhi[oh + LAT] = h;
      nlo[oh] = l; nlo[oh + LAT] = l;
    }
  }
}

// ---------- one persistent kernel for the whole recurrence ----------
template<bool PLANES>
__global__ __launch_bounds__(256, 1) void fused_seq_k(
    const u16* __restrict__ w1h, const u16* __restrict__ w1l,
    const u16* __restrict__ w2h, const u16* __restrict__ w2l,
    const float* __restrict__ b1, const float* __restrict__ b2,
    u16* __restrict__ c0h, u16* __restrict__ c0l,
    u16* __restrict__ c1h, u16* __restrict__ c1l,
    u16* __restrict__ h1h, u16* __restrict__ h1l,
    const float* __restrict__ whh, const u16* __restrict__ whhh, const u16* __restrict__ whhl,
    const float* __restrict__ wih, const u16* __restrict__ wihh, const u16* __restrict__ wihl,
    const float* __restrict__ bih, const float* __restrict__ bhh,
    const float* __restrict__ data, float* __restrict__ out,
    unsigned* __restrict__ bar)
{
  __shared__ u16 pool[20480];   // 40 KB, carved per phase
  const int b = blockIdx.x;
  const int tid = threadIdx.x;
  unsigned rnd = 0;

  for (int t = 0; t < LSEQ; ++t) {
    u16* chi = (t & 1) ? c1h : c0h;
    u16* clo = (t & 1) ? c1l : c0l;
    u16* nhi = (t & 1) ? c0h : c1h;
    u16* nlo = (t & 1) ? c0l : c1l;
    for (int s = 0; s < 3; ++s) {
      {  // mlp1: 256 tiles of 32x32 -> h1 = tanh(y @ w1 + b1)
        const int n0 = (b & 31) << 5, m0 = (b >> 5) << 5;
        gemm_phase<1>(pool, pool + 2560, 1280, pool + 5120, pool + 7680, 1280,
                      chi, clo, HID, m0, w1h, w1l, 512, n0, 512,
                      b1, h1h, h1l, data, t, tid);
      }
      grid_barrier(bar, rnd);
      if (b < 128) {  // mlp2: 128 tiles of 32x32 -> y += (h1 @ w2 + b2)*dt/3
        const int n0 = (b & 15) << 5, m0 = (b >> 4) << 5;
        gemm_phase<2>(pool, pool + 2560, 1280, pool + 5120, pool + 7680, 1280,
                      h1h, h1l, HID, m0, w2h, w2l, 1024, n0, 1024,
                      b2, chi, clo, data, t, tid);
      }
      grid_barrier(bar, rnd);
    }
    gru_phase<PLANES>(pool, chi, clo, whh, whhh, whhl, wih, wihh, wihl,
                      bih, bhh, data, t, nhi, nlo, out, b, tid);
    if (t + 1 < LSEQ) grid_barrier(bar, rnd);
  }
}

extern "C" void kernel_launch(void* const* d_in, const int* in_sizes, int n_in,
                              void* d_out, int out_size, void* d_ws, size_t ws_size,
                              hipStream_t stream)
{
  const float* data = (const float*)d_in[0];
  const float* w1   = (const float*)d_in[1];
  const float* b1   = (const float*)d_in[2];
  const float* w2   = (const float*)d_in[3];
  const float* b2   = (const float*)d_in[4];
  const float* wih  = (const float*)d_in[5];
  const float* bih  = (const float*)d_in[6];
  const float* whh  = (const float*)d_in[7];
  const float* bhh  = (const float*)d_in[8];
  float* out = (float*)d_out;

  char* w = (char*)d_ws;
  auto alloc = [&](size_t bytes) { char* p = w; w += bytes; return p; };
  u16* w1h = (u16*)alloc((size_t)512 * 1024 * 2);   // [1024 n][512 k] planes
  u16* w1l = (u16*)alloc((size_t)512 * 1024 * 2);
  u16* w2h = (u16*)alloc((size_t)512 * 1024 * 2);   // [512 n][1024 k] planes
  u16* w2l = (u16*)alloc((size_t)512 * 1024 * 2);
  u16* c0h = (u16*)alloc((size_t)BATCH * HID * 2);
  u16* c0l = (u16*)alloc((size_t)BATCH * HID * 2);
  u16* c1h = (u16*)alloc((size_t)BATCH * HID * 2);
  u16* c1l = (u16*)alloc((size_t)BATCH * HID * 2);
  u16* h1h = (u16*)alloc((size_t)BATCH * HID * 2);
  u16* h1l = (u16*)alloc((size_t)BATCH * HID * 2);
  unsigned* bar = (unsigned*)alloc(256);             // barrier state (monotonic counter)
  size_t base = (size_t)(w - (char*)d_ws);
  size_t need_opt = base + 2 * ((size_t)3072 * 1024 * 2) + 2 * ((size_t)3072 * 256 * 2);
  bool planes = ws_size >= need_opt;
  u16 *whhh = nullptr, *whhl = nullptr, *wihh = nullptr, *wihl = nullptr;
  if (planes) {
    whhh = (u16*)alloc((size_t)3072 * 1024 * 2);
    whhl = (u16*)alloc((size_t)3072 * 1024 * 2);
    wihh = (u16*)alloc((size_t)3072 * 256 * 2);
    wihl = (u16*)alloc((size_t)3072 * 256 * 2);
  }

  tsplit_k<<<dim3(512 / 32, 1024 / 32), 256, 0, stream>>>(w1, w1h, w1l, 512, 1024);
  tsplit_k<<<dim3(1024 / 32, 512 / 32), 256, 0, stream>>>(w2, w2h, w2l, 1024, 512);
  if (planes) {
    esplit_k<<<dim3((3072 * 1024) / 1024), 256, 0, stream>>>(whh, whhh, whhl);
    esplit_k<<<dim3((3072 * 256) / 1024), 256, 0, stream>>>(wih, wihh, wihl);
  }
  init_k<<<dim3(256), 256, 0, stream>>>(c0h, c0l, bar);

  if (planes) {
    fused_seq_k<true><<<dim3(NBLK), dim3(256), 0, stream>>>(
        w1h, w1l, w2h, w2l, b1, b2, c0h, c0l, c1h, c1l, h1h, h1l,
        whh, whhh, whhl, wih, wihh, wihl, bih, bhh, data, out, bar);
  } else {
    fused_seq_k<false><<<dim3(NBLK), dim3(256), 0, stream>>>(
        w1h, w1l, w2h, w2l, b1, b2, c0h, c0l, c1h, c1l, h1h, h1l,
        whh, whhh, whhl, wih, wihh, wihl, bih, bhh, data, out, bar);
  }
}

// Round 5
// 6381.483 us; speedup vs baseline: 3.2812x; 1.6066x over previous
//
#include <hip/hip_runtime.h>

#define LSEQ 50
#define BATCH 256
#define DIN 256
#define LAT 512
#define HID 1024
#define ROWSTRIDE 257  // D_IN + 1 (dt channel)
#define NBLK 256

typedef __attribute__((ext_vector_type(8))) short s16x8;
typedef __attribute__((ext_vector_type(4))) float f32x4;
using u16 = unsigned short;
using u64 = unsigned long long;

__device__ __forceinline__ u16 bfhi(float v) {
  union { float f; unsigned u; } a; a.f = v;
  return (u16)((a.u + 0x7FFFu + ((a.u >> 16) & 1u)) >> 16);
}
__device__ __forceinline__ void split2(float v, u16& h, u16& l) {
  u16 hu = bfhi(v);
  union { unsigned u; float f; } hf; hf.u = ((unsigned)hu) << 16;
  h = hu; l = bfhi(v - hf.f);
}
__device__ __forceinline__ float p2f(u16 h, u16 l) {
  union { unsigned u; float f; } a, b;
  a.u = ((unsigned)h) << 16; b.u = ((unsigned)l) << 16;
  return a.f + b.f;
}
__device__ __forceinline__ float sigmoidf_(float x) { return 1.f / (1.f + __expf(-x)); }
__device__ __forceinline__ f32x4 mfma16(s16x8 a, s16x8 b, f32x4 c) {
  return __builtin_amdgcn_mfma_f32_16x16x32_bf16(a, b, c, 0, 0, 0);
}
__device__ __forceinline__ ushort4 ldu4(const u16* p) { return *(const ushort4*)p; }
__device__ __forceinline__ void stu4(u16* p, ushort4 v) { *(ushort4*)p = v; }

// ---------- coherent (LLC-authoritative) accessors for cross-block state ----------
// Agent-scope relaxed atomics bypass the non-coherent per-XCD L2 by construction.
__device__ __forceinline__ ushort4 ldu4c(const u16* p) {
  u64 v = __hip_atomic_load((const u64*)p, __ATOMIC_RELAXED, __HIP_MEMORY_SCOPE_AGENT);
  union { u64 q; ushort4 s; } u; u.q = v; return u.s;
}
__device__ __forceinline__ u16 ldu16c(const u16* p) {
  return __hip_atomic_load(p, __ATOMIC_RELAXED, __HIP_MEMORY_SCOPE_AGENT);
}
__device__ __forceinline__ void stu16c(u16* p, u16 v) {
  __hip_atomic_store(p, v, __ATOMIC_RELAXED, __HIP_MEMORY_SCOPE_AGENT);
}

// ---------- grid barrier: no cache-wide fences, 8-way-spread arrive, replicated epoch ----------
// bar layout (unsigned): leaf[i] at bar[i*64] (i<8), epoch[i] at bar[(8+i)*64].
// Monotonic counters; zeroed by init_k each invocation. All cross-block payload is
// written with sc-coherent atomic stores, whose completion (vmcnt drain inside
// __syncthreads) implies visibility at the coherence point -> no wbl2/inv needed.
__device__ __forceinline__ void grid_barrier(unsigned* bar, unsigned k, int b) {
  asm volatile("s_waitcnt vmcnt(0)" ::: "memory");
  __syncthreads();
  if (threadIdx.x == 0) {
    __hip_atomic_fetch_add(bar + (b & 7) * 64, 1u, __ATOMIC_RELAXED, __HIP_MEMORY_SCOPE_AGENT);
    if (b == 0) {
      for (;;) {
        unsigned s = 0;
        #pragma unroll
        for (int i = 0; i < 8; ++i)
          s += __hip_atomic_load(bar + i * 64, __ATOMIC_RELAXED, __HIP_MEMORY_SCOPE_AGENT);
        if (s >= k * NBLK) break;
        __builtin_amdgcn_s_sleep(2);
      }
      #pragma unroll
      for (int i = 0; i < 8; ++i)
        __hip_atomic_store(bar + (8 + i) * 64, k, __ATOMIC_RELAXED, __HIP_MEMORY_SCOPE_AGENT);
    } else {
      unsigned* ep = bar + (8 + (b & 7)) * 64;
      while (__hip_atomic_load(ep, __ATOMIC_RELAXED, __HIP_MEMORY_SCOPE_AGENT) < k) {
        __builtin_amdgcn_s_sleep(2);
      }
    }
  }
  __syncthreads();
}

// ---------- preprocessing (round-0 verbatim) ----------
__global__ __launch_bounds__(256) void tsplit_k(const float* __restrict__ W,
    u16* __restrict__ Thi, u16* __restrict__ Tlo, int K, int N)
{
  __shared__ unsigned Ts[32][33];
  const int bk = blockIdx.x * 32, bn = blockIdx.y * 32;
  const int t = threadIdx.x;
  const int n_l = t & 31, k_l4 = (t >> 5) * 4;
  #pragma unroll
  for (int i = 0; i < 4; i++) {
    float v = W[(size_t)(bk + k_l4 + i) * N + bn + n_l];
    u16 h, l; split2(v, h, l);
    Ts[k_l4 + i][n_l] = ((unsigned)h << 16) | l;
  }
  __syncthreads();
  const int k_l = t & 31, n_l2 = t >> 5;
  #pragma unroll
  for (int i = 0; i < 4; i++) {
    int nn = n_l2 + 8 * i;
    unsigned u = Ts[k_l][nn];
    size_t o = (size_t)(bn + nn) * K + bk + k_l;
    Thi[o] = (u16)(u >> 16);
    Tlo[o] = (u16)(u & 0xFFFFu);
  }
}

__global__ __launch_bounds__(256) void esplit_k(const float* __restrict__ W,
    u16* __restrict__ Phi, u16* __restrict__ Plo)
{
  size_t i4 = ((size_t)blockIdx.x * 256 + threadIdx.x) * 4;
  float4 v = *(const float4*)&W[i4];
  u16 h[4], l[4];
  split2(v.x, h[0], l[0]); split2(v.y, h[1], l[1]);
  split2(v.z, h[2], l[2]); split2(v.w, h[3], l[3]);
  *(ushort4*)&Phi[i4] = make_ushort4(h[0], h[1], h[2], h[3]);
  *(ushort4*)&Plo[i4] = make_ushort4(l[0], l[1], l[2], l[3]);
}

__global__ __launch_bounds__(256) void init_k(u16* __restrict__ c0h, u16* __restrict__ c0l,
                                              unsigned* __restrict__ bar)
{
  size_t i4 = ((size_t)blockIdx.x * 256 + threadIdx.x) * 4;
  *(ushort4*)&c0h[i4] = make_ushort4(0, 0, 0, 0);
  *(ushort4*)&c0l[i4] = make_ushort4(0, 0, 0, 0);
  if (blockIdx.x == 0 && threadIdx.x < 16) bar[threadIdx.x * 64] = 0u;
}

// ---------- double-buffered split-bf16 GEMM phase ----------
// A = cross-block state (coherent loads); B = read-only weights (plain, L2-cached).
// EPI 1: O planes = split(tanh(acc + bias))
// EPI 2: y = p2f(O planes) + (acc + bias)*dt/3; O planes = split(y)
template<int EPI>
__device__ __forceinline__ void gemm_phase(
    u16* Sah, u16* Sal, int sA, u16* Sbh, u16* Sbl, int sB,
    const u16* __restrict__ Ahi, const u16* __restrict__ Alo, int ldA, int m0,
    const u16* __restrict__ Bhi, const u16* __restrict__ Blo, int ldB, int n0,
    int K, const float* __restrict__ bias,
    u16* __restrict__ Ohi, u16* __restrict__ Olo,
    const float* __restrict__ data, int t, int tid)
{
  const int lane = tid & 63, wave = tid >> 6;
  const int wm = (wave >> 1) << 4, wn = (wave & 1) << 4;
  const int lr = lane & 15, lq = lane >> 4;
  const int srow = tid >> 3, sk4 = (tid & 7) << 2;
  const int sidx = srow * 40 + sk4;
  f32x4 acc = {0.f, 0.f, 0.f, 0.f};
  {
    size_t oa = (size_t)(m0 + srow) * ldA + sk4;
    size_t ob = (size_t)(n0 + srow) * ldB + sk4;
    stu4(&Sah[sidx], ldu4c(&Ahi[oa])); stu4(&Sal[sidx], ldu4c(&Alo[oa]));
    stu4(&Sbh[sidx], ldu4(&Bhi[ob])); stu4(&Sbl[sidx], ldu4(&Blo[ob]));
  }
  __syncthreads();
  const int niter = K >> 5;
  for (int it = 0; it < niter; ++it) {
    const int db = it & 1, nb = db ^ 1;
    const bool pf = (it + 1 < niter);
    ushort4 nah, nal, nbh, nbl;
    if (pf) {
      const int k0 = (it + 1) << 5;
      size_t oa = (size_t)(m0 + srow) * ldA + k0 + sk4;
      size_t ob = (size_t)(n0 + srow) * ldB + k0 + sk4;
      nah = ldu4c(&Ahi[oa]); nal = ldu4c(&Alo[oa]);
      nbh = ldu4(&Bhi[ob]); nbl = ldu4(&Blo[ob]);
    }
    const int fa = db * sA + (wm + lr) * 40 + lq * 8;
    const int fb = db * sB + (wn + lr) * 40 + lq * 8;
    s16x8 ah = *(const s16x8*)&Sah[fa];
    s16x8 al = *(const s16x8*)&Sal[fa];
    s16x8 bh = *(const s16x8*)&Sbh[fb];
    s16x8 bl = *(const s16x8*)&Sbl[fb];
    acc = mfma16(ah, bh, acc);
    acc = mfma16(ah, bl, acc);
    acc = mfma16(al, bh, acc);
    if (pf) {
      stu4(&Sah[nb * sA + sidx], nah); stu4(&Sal[nb * sA + sidx], nal);
      stu4(&Sbh[nb * sB + sidx], nbh); stu4(&Sbl[nb * sB + sidx], nbl);
    }
    __syncthreads();
  }
  #pragma unroll
  for (int r = 0; r < 4; ++r) {
    const int row = m0 + wm + lq * 4 + r;
    const int col = n0 + wn + lr;
    float v = acc[r] + bias[col];
    size_t o = (size_t)row * HID + col;
    if (EPI == 1) {
      float h1 = tanhf(v);
      u16 h, l; split2(h1, h, l);
      stu16c(&Ohi[o], h); stu16c(&Olo[o], l);
    } else {
      float dt3 = data[(size_t)(t * BATCH + row) * ROWSTRIDE + DIN] * (1.f / 3.f);
      float y = p2f(ldu16c(&Ohi[o]), ldu16c(&Olo[o])) + v * dt3;
      u16 h, l; split2(y, h, l);
      stu16c(&Ohi[o], h); stu16c(&Olo[o], l);
    }
  }
}

// ---------- fused GRU phase ----------
template<bool PLANES>
__device__ __forceinline__ void gru_phase(
    u16* pool,
    const u16* __restrict__ chi, const u16* __restrict__ clo,
    const float* __restrict__ whh, const u16* __restrict__ whhh, const u16* __restrict__ whhl,
    const float* __restrict__ wih, const u16* __restrict__ wihh, const u16* __restrict__ wihl,
    const float* __restrict__ bih, const float* __restrict__ bhh,
    const float* __restrict__ data, int t,
    u16* __restrict__ nhi, u16* __restrict__ nlo,
    float* __restrict__ out, int b, int tid)
{
  u16* sAh = pool;            // 2*1280
  u16* sAl = pool + 2560;     // 2*1280
  u16* sBh = pool + 5120;     // 2*3840
  u16* sBl = pool + 12800;    // 2*3840
  const int g0 = (b & 31) << 5, m0 = (b >> 5) << 5;
  const int lane = tid & 63, wave = tid >> 6;
  const int wm = (wave >> 1) << 4, wn = (wave & 1) << 4;
  const int lr = lane & 15, lq = lane >> 4;
  const int srow = tid >> 3, sk4 = (tid & 7) << 2;
  const int sidx = srow * 40 + sk4;

  f32x4 aR = {0,0,0,0}, aZ = {0,0,0,0}, aNh = {0,0,0,0}, aNi = {0,0,0,0};
  // phase 0 preload (K-tile 0)
  {
    size_t oa = (size_t)(m0 + srow) * HID + sk4;
    stu4(&sAh[sidx], ldu4c(&chi[oa])); stu4(&sAl[sidx], ldu4c(&clo[oa]));
    #pragma unroll
    for (int g = 0; g < 3; ++g) {
      const size_t rrow = (size_t)(g * 1024 + g0 + srow);
      if (PLANES) {
        size_t ob = rrow * 1024 + sk4;
        stu4(&sBh[g * 1280 + sidx], ldu4(&whhh[ob]));
        stu4(&sBl[g * 1280 + sidx], ldu4(&whhl[ob]));
      } else {
        float4 w4 = *(const float4*)&whh[rrow * 1024 + sk4];
        u16 h0,l0,h1,l1,h2,l2,h3,l3;
        split2(w4.x,h0,l0); split2(w4.y,h1,l1); split2(w4.z,h2,l2); split2(w4.w,h3,l3);
        stu4(&sBh[g * 1280 + sidx], make_ushort4(h0,h1,h2,h3));
        stu4(&sBl[g * 1280 + sidx], make_ushort4(l0,l1,l2,l3));
      }
    }
  }
  __syncthreads();
  for (int it = 0; it < 32; ++it) {
    const int db = it & 1, nb = db ^ 1;
    const bool pf = (it + 1 < 32);
    ushort4 nah, nal, nb0h, nb0l, nb1h, nb1l, nb2h, nb2l;
    if (pf) {
      const int k0 = (it + 1) << 5;
      size_t oa = (size_t)(m0 + srow) * HID + k0 + sk4;
      nah = ldu4c(&chi[oa]); nal = ldu4c(&clo[oa]);
      if (PLANES) {
        size_t r0 = (size_t)(0 * 1024 + g0 + srow) * 1024 + k0 + sk4;
        size_t r1 = (size_t)(1 * 1024 + g0 + srow) * 1024 + k0 + sk4;
        size_t r2 = (size_t)(2 * 1024 + g0 + srow) * 1024 + k0 + sk4;
        nb0h = ldu4(&whhh[r0]); nb0l = ldu4(&whhl[r0]);
        nb1h = ldu4(&whhh[r1]); nb1l = ldu4(&whhl[r1]);
        nb2h = ldu4(&whhh[r2]); nb2l = ldu4(&whhl[r2]);
      } else {
        #pragma unroll
        for (int g = 0; g < 3; ++g) {
          float4 w4 = *(const float4*)&whh[(size_t)(g * 1024 + g0 + srow) * 1024 + k0 + sk4];
          u16 h0,l0,h1,l1,h2,l2,h3,l3;
          split2(w4.x,h0,l0); split2(w4.y,h1,l1); split2(w4.z,h2,l2); split2(w4.w,h3,l3);
          ushort4 hh = make_ushort4(h0,h1,h2,h3), ll = make_ushort4(l0,l1,l2,l3);
          if (g == 0) { nb0h = hh; nb0l = ll; }
          else if (g == 1) { nb1h = hh; nb1l = ll; }
          else { nb2h = hh; nb2l = ll; }
        }
      }
    }
    const int fa = db * 1280 + (wm + lr) * 40 + lq * 8;
    s16x8 ah = *(const s16x8*)&sAh[fa];
    s16x8 al = *(const s16x8*)&sAl[fa];
    #pragma unroll
    for (int g = 0; g < 3; ++g) {
      const int fb = db * 3840 + g * 1280 + (wn + lr) * 40 + lq * 8;
      s16x8 bh = *(const s16x8*)&sBh[fb];
      s16x8 bl = *(const s16x8*)&sBl[fb];
      f32x4 c = (g == 0) ? aR : (g == 1) ? aZ : aNh;
      c = mfma16(ah, bh, c); c = mfma16(ah, bl, c); c = mfma16(al, bh, c);
      if (g == 0) aR = c; else if (g == 1) aZ = c; else aNh = c;
    }
    if (pf) {
      stu4(&sAh[nb * 1280 + sidx], nah); stu4(&sAl[nb * 1280 + sidx], nal);
      stu4(&sBh[nb * 3840 + 0 * 1280 + sidx], nb0h); stu4(&sBl[nb * 3840 + 0 * 1280 + sidx], nb0l);
      stu4(&sBh[nb * 3840 + 1 * 1280 + sidx], nb1h); stu4(&sBl[nb * 3840 + 1 * 1280 + sidx], nb1l);
      stu4(&sBh[nb * 3840 + 2 * 1280 + sidx], nb2h); stu4(&sBl[nb * 3840 + 2 * 1280 + sidx], nb2l);
    }
    __syncthreads();
  }
  // phase 1: gi (x_t split on the fly), K = 256
  {
    const float* xp = &data[(size_t)(t * BATCH + m0 + srow) * ROWSTRIDE + sk4];
    u16 xh[4], xl[4];
    #pragma unroll
    for (int i = 0; i < 4; i++) split2(xp[i], xh[i], xl[i]);
    stu4(&sAh[sidx], make_ushort4(xh[0], xh[1], xh[2], xh[3]));
    stu4(&sAl[sidx], make_ushort4(xl[0], xl[1], xl[2], xl[3]));
    #pragma unroll
    for (int g = 0; g < 3; ++g) {
      const size_t rrow = (size_t)(g * 1024 + g0 + srow);
      if (PLANES) {
        size_t ob = rrow * 256 + sk4;
        stu4(&sBh[g * 1280 + sidx], ldu4(&wihh[ob]));
        stu4(&sBl[g * 1280 + sidx], ldu4(&wihl[ob]));
      } else {
        float4 w4 = *(const float4*)&wih[rrow * 256 + sk4];
        u16 h0,l0,h1,l1,h2,l2,h3,l3;
        split2(w4.x,h0,l0); split2(w4.y,h1,l1); split2(w4.z,h2,l2); split2(w4.w,h3,l3);
        stu4(&sBh[g * 1280 + sidx], make_ushort4(h0,h1,h2,h3));
        stu4(&sBl[g * 1280 + sidx], make_ushort4(l0,l1,l2,l3));
      }
    }
  }
  __syncthreads();
  for (int it = 0; it < 8; ++it) {
    const int db = it & 1, nb = db ^ 1;
    const bool pf = (it + 1 < 8);
    ushort4 nah, nal, nb0h, nb0l, nb1h, nb1l, nb2h, nb2l;
    if (pf) {
      const int k0 = (it + 1) << 5;
      const float* xp = &data[(size_t)(t * BATCH + m0 + srow) * ROWSTRIDE + k0 + sk4];
      u16 xh[4], xl[4];
      #pragma unroll
      for (int i = 0; i < 4; i++) split2(xp[i], xh[i], xl[i]);
      nah = make_ushort4(xh[0], xh[1], xh[2], xh[3]);
      nal = make_ushort4(xl[0], xl[1], xl[2], xl[3]);
      if (PLANES) {
        size_t r0 = (size_t)(0 * 1024 + g0 + srow) * 256 + k0 + sk4;
        size_t r1 = (size_t)(1 * 1024 + g0 + srow) * 256 + k0 + sk4;
        size_t r2 = (size_t)(2 * 1024 + g0 + srow) * 256 + k0 + sk4;
        nb0h = ldu4(&wihh[r0]); nb0l = ldu4(&wihl[r0]);
        nb1h = ldu4(&wihh[r1]); nb1l = ldu4(&wihl[r1]);
        nb2h = ldu4(&wihh[r2]); nb2l = ldu4(&wihl[r2]);
      } else {
        #pragma unroll
        for (int g = 0; g < 3; ++g) {
          float4 w4 = *(const float4*)&wih[(size_t)(g * 1024 + g0 + srow) * 256 + k0 + sk4];
          u16 h0,l0,h1,l1,h2,l2,h3,l3;
          split2(w4.x,h0,l0); split2(w4.y,h1,l1); split2(w4.z,h2,l2); split2(w4.w,h3,l3);
          ushort4 hh = make_ushort4(h0,h1,h2,h3), ll = make_ushort4(l0,l1,l2,l3);
          if (g == 0) { nb0h = hh; nb0l = ll; }
          else if (g == 1) { nb1h = hh; nb1l = ll; }
          else { nb2h = hh; nb2l = ll; }
        }
      }
    }
    const int fa = db * 1280 + (wm + lr) * 40 + lq * 8;
    s16x8 ah = *(const s16x8*)&sAh[fa];
    s16x8 al = *(const s16x8*)&sAl[fa];
    #pragma unroll
    for (int g = 0; g < 3; ++g) {
      const int fb = db * 3840 + g * 1280 + (wn + lr) * 40 + lq * 8;
      s16x8 bh = *(const s16x8*)&sBh[fb];
      s16x8 bl = *(const s16x8*)&sBl[fb];
      f32x4 c = (g == 0) ? aR : (g == 1) ? aZ : aNi;
      c = mfma16(ah, bh, c); c = mfma16(ah, bl, c); c = mfma16(al, bh, c);
      if (g == 0) aR = c; else if (g == 1) aZ = c; else aNi = c;
    }
    if (pf) {
      stu4(&sAh[nb * 1280 + sidx], nah); stu4(&sAl[nb * 1280 + sidx], nal);
      stu4(&sBh[nb * 3840 + 0 * 1280 + sidx], nb0h); stu4(&sBl[nb * 3840 + 0 * 1280 + sidx], nb0l);
      stu4(&sBh[nb * 3840 + 1 * 1280 + sidx], nb1h); stu4(&sBl[nb * 3840 + 1 * 1280 + sidx], nb1l);
      stu4(&sBh[nb * 3840 + 2 * 1280 + sidx], nb2h); stu4(&sBl[nb * 3840 + 2 * 1280 + sidx], nb2l);
    }
    __syncthreads();
  }
  // epilogue: pointwise GRU + outputs + next state
  #pragma unroll
  for (int r = 0; r < 4; ++r) {
    const int row = m0 + wm + lq * 4 + r;
    const int jg = g0 + wn + lr;
    float rr = sigmoidf_(aR[r] + bih[jg] + bhh[jg]);
    float zz = sigmoidf_(aZ[r] + bih[1024 + jg] + bhh[1024 + jg]);
    float nn = tanhf(aNi[r] + bih[2048 + jg] + rr * (aNh[r] + bhh[2048 + jg]));
    size_t oh = (size_t)row * HID + jg;
    float hv = p2f(ldu16c(&chi[oh]), ldu16c(&clo[oh]));
    float val = (1.f - zz) * nn + zz * hv;
    out[(size_t)LSEQ * BATCH * LAT + oh] = val;        // output 1 (new_h)
    if (jg < LAT) {
      out[((size_t)t * BATCH + row) * LAT + jg] = val; // output 0
      u16 h, l; split2(val, h, l);
      stu16c(&nhi[oh], h); stu16c(&nhi[oh + LAT], h);
      stu16c(&nlo[oh], l); stu16c(&nlo[oh + LAT], l);
    }
  }
}

// ---------- one persistent kernel for the whole recurrence ----------
template<bool PLANES>
__global__ __launch_bounds__(256, 1) void fused_seq_k(
    const u16* __restrict__ w1h, const u16* __restrict__ w1l,
    const u16* __restrict__ w2h, const u16* __restrict__ w2l,
    const float* __restrict__ b1, const float* __restrict__ b2,
    u16* __restrict__ c0h, u16* __restrict__ c0l,
    u16* __restrict__ c1h, u16* __restrict__ c1l,
    u16* __restrict__ h1h, u16* __restrict__ h1l,
    const float* __restrict__ whh, const u16* __restrict__ whhh, const u16* __restrict__ whhl,
    const float* __restrict__ wih, const u16* __restrict__ wihh, const u16* __restrict__ wihl,
    const float* __restrict__ bih, const float* __restrict__ bhh,
    const float* __restrict__ data, float* __restrict__ out,
    unsigned* __restrict__ bar)
{
  __shared__ u16 pool[20480];   // 40 KB, carved per phase
  const int b = blockIdx.x;
  const int tid = threadIdx.x;
  unsigned rnd = 0;

  for (int t = 0; t < LSEQ; ++t) {
    u16* chi = (t & 1) ? c1h : c0h;
    u16* clo = (t & 1) ? c1l : c0l;
    u16* nhi = (t & 1) ? c0h : c1h;
    u16* nlo = (t & 1) ? c0l : c1l;
    for (int s = 0; s < 3; ++s) {
      {  // mlp1: 256 tiles of 32x32 -> h1 = tanh(y @ w1 + b1)
        const int n0 = (b & 31) << 5, m0 = (b >> 5) << 5;
        gemm_phase<1>(pool, pool + 2560, 1280, pool + 5120, pool + 7680, 1280,
                      chi, clo, HID, m0, w1h, w1l, 512, n0, 512,
                      b1, h1h, h1l, data, t, tid);
      }
      ++rnd; grid_barrier(bar, rnd, b);
      if (b < 128) {  // mlp2: 128 tiles of 32x32 -> y += (h1 @ w2 + b2)*dt/3
        const int n0 = (b & 15) << 5, m0 = (b >> 4) << 5;
        gemm_phase<2>(pool, pool + 2560, 1280, pool + 5120, pool + 7680, 1280,
                      h1h, h1l, HID, m0, w2h, w2l, 1024, n0, 1024,
                      b2, chi, clo, data, t, tid);
      }
      ++rnd; grid_barrier(bar, rnd, b);
    }
    gru_phase<PLANES>(pool, chi, clo, whh, whhh, whhl, wih, wihh, wihl,
                      bih, bhh, data, t, nhi, nlo, out, b, tid);
    if (t + 1 < LSEQ) { ++rnd; grid_barrier(bar, rnd, b); }
  }
}

extern "C" void kernel_launch(void* const* d_in, const int* in_sizes, int n_in,
                              void* d_out, int out_size, void* d_ws, size_t ws_size,
                              hipStream_t stream)
{
  const float* data = (const float*)d_in[0];
  const float* w1   = (const float*)d_in[1];
  const float* b1   = (const float*)d_in[2];
  const float* w2   = (const float*)d_in[3];
  const float* b2   = (const float*)d_in[4];
  const float* wih  = (const float*)d_in[5];
  const float* bih  = (const float*)d_in[6];
  const float* whh  = (const float*)d_in[7];
  const float* bhh  = (const float*)d_in[8];
  float* out = (float*)d_out;

  char* w = (char*)d_ws;
  auto alloc = [&](size_t bytes) { char* p = w; w += bytes; return p; };
  u16* w1h = (u16*)alloc((size_t)512 * 1024 * 2);   // [1024 n][512 k] planes
  u16* w1l = (u16*)alloc((size_t)512 * 1024 * 2);
  u16* w2h = (u16*)alloc((size_t)512 * 1024 * 2);   // [512 n][1024 k] planes
  u16* w2l = (u16*)alloc((size_t)512 * 1024 * 2);
  u16* c0h = (u16*)alloc((size_t)BATCH * HID * 2);
  u16* c0l = (u16*)alloc((size_t)BATCH * HID * 2);
  u16* c1h = (u16*)alloc((size_t)BATCH * HID * 2);
  u16* c1l = (u16*)alloc((size_t)BATCH * HID * 2);
  u16* h1h = (u16*)alloc((size_t)BATCH * HID * 2);
  u16* h1l = (u16*)alloc((size_t)BATCH * HID * 2);
  unsigned* bar = (unsigned*)alloc(4096);            // 16 counter lines, 256B apart
  size_t base = (size_t)(w - (char*)d_ws);
  size_t need_opt = base + 2 * ((size_t)3072 * 1024 * 2) + 2 * ((size_t)3072 * 256 * 2);
  bool planes = ws_size >= need_opt;
  u16 *whhh = nullptr, *whhl = nullptr, *wihh = nullptr, *wihl = nullptr;
  if (planes) {
    whhh = (u16*)alloc((size_t)3072 * 1024 * 2);
    whhl = (u16*)alloc((size_t)3072 * 1024 * 2);
    wihh = (u16*)alloc((size_t)3072 * 256 * 2);
    wihl = (u16*)alloc((size_t)3072 * 256 * 2);
  }

  tsplit_k<<<dim3(512 / 32, 1024 / 32), 256, 0, stream>>>(w1, w1h, w1l, 512, 1024);
  tsplit_k<<<dim3(1024 / 32, 512 / 32), 256, 0, stream>>>(w2, w2h, w2l, 1024, 512);
  if (planes) {
    esplit_k<<<dim3((3072 * 1024) / 1024), 256, 0, stream>>>(whh, whhh, whhl);
    esplit_k<<<dim3((3072 * 256) / 1024), 256, 0, stream>>>(wih, wihh, wihl);
  }
  init_k<<<dim3(256), 256, 0, stream>>>(c0h, c0l, bar);

  if (planes) {
    fused_seq_k<true><<<dim3(NBLK), dim3(256), 0, stream>>>(
        w1h, w1l, w2h, w2l, b1, b2, c0h, c0l, c1h, c1l, h1h, h1l,
        whh, whhh, whhl, wih, wihh, wihl, bih, bhh, data, out, bar);
  } else {
    fused_seq_k<false><<<dim3(NBLK), dim3(256), 0, stream>>>(
        w1h, w1l, w2h, w2l, b1, b2, c0h, c0l, c1h, c1l, h1h, h1l,
        whh, whhh, whhl, wih, wihh, wihl, bih, bhh, data, out, bar);
  }
}

// Round 6
// 6006.293 us; speedup vs baseline: 3.4862x; 1.0625x over previous
//
#include <hip/hip_runtime.h>

#define LSEQ 50
#define BATCH 256
#define DIN 256
#define LAT 512
#define HID 1024
#define ROWSTRIDE 257  // D_IN + 1 (dt channel)
#define NBLK 256

typedef __attribute__((ext_vector_type(8))) short s16x8;
typedef __attribute__((ext_vector_type(4))) float f32x4;
using u16 = unsigned short;
using u64 = unsigned long long;

__device__ __forceinline__ u16 bfhi(float v) {
  union { float f; unsigned u; } a; a.f = v;
  return (u16)((a.u + 0x7FFFu + ((a.u >> 16) & 1u)) >> 16);
}
__device__ __forceinline__ void split2(float v, u16& h, u16& l) {
  u16 hu = bfhi(v);
  union { unsigned u; float f; } hf; hf.u = ((unsigned)hu) << 16;
  h = hu; l = bfhi(v - hf.f);
}
__device__ __forceinline__ float p2f(u16 h, u16 l) {
  union { unsigned u; float f; } a, b;
  a.u = ((unsigned)h) << 16; b.u = ((unsigned)l) << 16;
  return a.f + b.f;
}
__device__ __forceinline__ float sigmoidf_(float x) { return 1.f / (1.f + __expf(-x)); }
__device__ __forceinline__ f32x4 mfma16(s16x8 a, s16x8 b, f32x4 c) {
  return __builtin_amdgcn_mfma_f32_16x16x32_bf16(a, b, c, 0, 0, 0);
}
__device__ __forceinline__ ushort4 ldu4(const u16* p) { return *(const ushort4*)p; }
__device__ __forceinline__ void stu4(u16* p, ushort4 v) { *(ushort4*)p = v; }

// ---------- coherent (LLC-authoritative) accessors for cross-block state ----------
// Agent-scope relaxed atomics bypass the non-coherent per-XCD L2 by construction.
__device__ __forceinline__ ushort4 ldu4c(const u16* p) {
  u64 v = __hip_atomic_load((const u64*)p, __ATOMIC_RELAXED, __HIP_MEMORY_SCOPE_AGENT);
  union { u64 q; ushort4 s; } u; u.q = v; return u.s;
}
__device__ __forceinline__ u16 ldu16c(const u16* p) {
  return __hip_atomic_load(p, __ATOMIC_RELAXED, __HIP_MEMORY_SCOPE_AGENT);
}
__device__ __forceinline__ void stu16c(u16* p, u16 v) {
  __hip_atomic_store(p, v, __ATOMIC_RELAXED, __HIP_MEMORY_SCOPE_AGENT);
}

// ---------- slice barrier: 32 blocks, one counter line, symmetric poll ----------
// The recurrence decomposes by batch rows: slice s = blocks [32s, 32s+32) touch only
// state rows [32s, 32s+32). No cross-slice data => no grid-wide sync ever needed.
// Payload stores are sc-coherent (LLC); vmcnt(0) drain before arrive makes their
// completion (ack from coherence point) precede the arrive. Consumer's payload loads
// are gated by the poll branch + __syncthreads.
__device__ __forceinline__ void slice_barrier(unsigned* line, unsigned k) {
  asm volatile("s_waitcnt vmcnt(0)" ::: "memory");
  __syncthreads();
  if (threadIdx.x == 0) {
    __hip_atomic_fetch_add(line, 1u, __ATOMIC_RELAXED, __HIP_MEMORY_SCOPE_AGENT);
    const unsigned tgt = k * 32u;
    while (__hip_atomic_load(line, __ATOMIC_RELAXED, __HIP_MEMORY_SCOPE_AGENT) < tgt) {
      __builtin_amdgcn_s_sleep(1);
    }
  }
  __syncthreads();
}

// ---------- preprocessing (round-0 verbatim) ----------
__global__ __launch_bounds__(256) void tsplit_k(const float* __restrict__ W,
    u16* __restrict__ Thi, u16* __restrict__ Tlo, int K, int N)
{
  __shared__ unsigned Ts[32][33];
  const int bk = blockIdx.x * 32, bn = blockIdx.y * 32;
  const int t = threadIdx.x;
  const int n_l = t & 31, k_l4 = (t >> 5) * 4;
  #pragma unroll
  for (int i = 0; i < 4; i++) {
    float v = W[(size_t)(bk + k_l4 + i) * N + bn + n_l];
    u16 h, l; split2(v, h, l);
    Ts[k_l4 + i][n_l] = ((unsigned)h << 16) | l;
  }
  __syncthreads();
  const int k_l = t & 31, n_l2 = t >> 5;
  #pragma unroll
  for (int i = 0; i < 4; i++) {
    int nn = n_l2 + 8 * i;
    unsigned u = Ts[k_l][nn];
    size_t o = (size_t)(bn + nn) * K + bk + k_l;
    Thi[o] = (u16)(u >> 16);
    Tlo[o] = (u16)(u & 0xFFFFu);
  }
}

__global__ __launch_bounds__(256) void esplit_k(const float* __restrict__ W,
    u16* __restrict__ Phi, u16* __restrict__ Plo)
{
  size_t i4 = ((size_t)blockIdx.x * 256 + threadIdx.x) * 4;
  float4 v = *(const float4*)&W[i4];
  u16 h[4], l[4];
  split2(v.x, h[0], l[0]); split2(v.y, h[1], l[1]);
  split2(v.z, h[2], l[2]); split2(v.w, h[3], l[3]);
  *(ushort4*)&Phi[i4] = make_ushort4(h[0], h[1], h[2], h[3]);
  *(ushort4*)&Plo[i4] = make_ushort4(l[0], l[1], l[2], l[3]);
}

__global__ __launch_bounds__(256) void init_k(u16* __restrict__ c0h, u16* __restrict__ c0l,
                                              unsigned* __restrict__ bar)
{
  size_t i4 = ((size_t)blockIdx.x * 256 + threadIdx.x) * 4;
  *(ushort4*)&c0h[i4] = make_ushort4(0, 0, 0, 0);
  *(ushort4*)&c0l[i4] = make_ushort4(0, 0, 0, 0);
  if (blockIdx.x == 0 && threadIdx.x < 16) bar[threadIdx.x * 64] = 0u;
}

// ---------- double-buffered split-bf16 GEMM phase ----------
// A = cross-block state (coherent loads); B = read-only weights (plain loads).
// EPI 1: O planes = split(tanh(acc + bias))
// EPI 2: y = p2f(O planes) + (acc + bias)*dt/3; O planes = split(y)
template<int EPI>
__device__ __forceinline__ void gemm_phase(
    u16* Sah, u16* Sal, int sA, u16* Sbh, u16* Sbl, int sB,
    const u16* __restrict__ Ahi, const u16* __restrict__ Alo, int ldA, int m0,
    const u16* __restrict__ Bhi, const u16* __restrict__ Blo, int ldB, int n0,
    int K, const float* __restrict__ bias,
    u16* __restrict__ Ohi, u16* __restrict__ Olo,
    const float* __restrict__ data, int t, int tid)
{
  const int lane = tid & 63, wave = tid >> 6;
  const int wm = (wave >> 1) << 4, wn = (wave & 1) << 4;
  const int lr = lane & 15, lq = lane >> 4;
  const int srow = tid >> 3, sk4 = (tid & 7) << 2;
  const int sidx = srow * 40 + sk4;
  f32x4 acc = {0.f, 0.f, 0.f, 0.f};
  {
    size_t oa = (size_t)(m0 + srow) * ldA + sk4;
    size_t ob = (size_t)(n0 + srow) * ldB + sk4;
    stu4(&Sah[sidx], ldu4c(&Ahi[oa])); stu4(&Sal[sidx], ldu4c(&Alo[oa]));
    stu4(&Sbh[sidx], ldu4(&Bhi[ob])); stu4(&Sbl[sidx], ldu4(&Blo[ob]));
  }
  __syncthreads();
  const int niter = K >> 5;
  for (int it = 0; it < niter; ++it) {
    const int db = it & 1, nb = db ^ 1;
    const bool pf = (it + 1 < niter);
    ushort4 nah, nal, nbh, nbl;
    if (pf) {
      const int k0 = (it + 1) << 5;
      size_t oa = (size_t)(m0 + srow) * ldA + k0 + sk4;
      size_t ob = (size_t)(n0 + srow) * ldB + k0 + sk4;
      nah = ldu4c(&Ahi[oa]); nal = ldu4c(&Alo[oa]);
      nbh = ldu4(&Bhi[ob]); nbl = ldu4(&Blo[ob]);
    }
    const int fa = db * sA + (wm + lr) * 40 + lq * 8;
    const int fb = db * sB + (wn + lr) * 40 + lq * 8;
    s16x8 ah = *(const s16x8*)&Sah[fa];
    s16x8 al = *(const s16x8*)&Sal[fa];
    s16x8 bh = *(const s16x8*)&Sbh[fb];
    s16x8 bl = *(const s16x8*)&Sbl[fb];
    acc = mfma16(ah, bh, acc);
    acc = mfma16(ah, bl, acc);
    acc = mfma16(al, bh, acc);
    if (pf) {
      stu4(&Sah[nb * sA + sidx], nah); stu4(&Sal[nb * sA + sidx], nal);
      stu4(&Sbh[nb * sB + sidx], nbh); stu4(&Sbl[nb * sB + sidx], nbl);
    }
    __syncthreads();
  }
  #pragma unroll
  for (int r = 0; r < 4; ++r) {
    const int row = m0 + wm + lq * 4 + r;
    const int col = n0 + wn + lr;
    float v = acc[r] + bias[col];
    size_t o = (size_t)row * HID + col;
    if (EPI == 1) {
      float h1 = tanhf(v);
      u16 h, l; split2(h1, h, l);
      stu16c(&Ohi[o], h); stu16c(&Olo[o], l);
    } else {
      float dt3 = data[(size_t)(t * BATCH + row) * ROWSTRIDE + DIN] * (1.f / 3.f);
      float y = p2f(ldu16c(&Ohi[o]), ldu16c(&Olo[o])) + v * dt3;
      u16 h, l; split2(y, h, l);
      stu16c(&Ohi[o], h); stu16c(&Olo[o], l);
    }
  }
}

// ---------- fused GRU phase ----------
template<bool PLANES>
__device__ __forceinline__ void gru_phase(
    u16* pool,
    const u16* __restrict__ chi, const u16* __restrict__ clo,
    const float* __restrict__ whh, const u16* __restrict__ whhh, const u16* __restrict__ whhl,
    const float* __restrict__ wih, const u16* __restrict__ wihh, const u16* __restrict__ wihl,
    const float* __restrict__ bih, const float* __restrict__ bhh,
    const float* __restrict__ data, int t,
    u16* __restrict__ nhi, u16* __restrict__ nlo,
    float* __restrict__ out, int g0, int m0, int tid)
{
  u16* sAh = pool;            // 2*1280
  u16* sAl = pool + 2560;     // 2*1280
  u16* sBh = pool + 5120;     // 2*3840
  u16* sBl = pool + 12800;    // 2*3840
  const int lane = tid & 63, wave = tid >> 6;
  const int wm = (wave >> 1) << 4, wn = (wave & 1) << 4;
  const int lr = lane & 15, lq = lane >> 4;
  const int srow = tid >> 3, sk4 = (tid & 7) << 2;
  const int sidx = srow * 40 + sk4;

  f32x4 aR = {0,0,0,0}, aZ = {0,0,0,0}, aNh = {0,0,0,0}, aNi = {0,0,0,0};
  // phase 0 preload (K-tile 0)
  {
    size_t oa = (size_t)(m0 + srow) * HID + sk4;
    stu4(&sAh[sidx], ldu4c(&chi[oa])); stu4(&sAl[sidx], ldu4c(&clo[oa]));
    #pragma unroll
    for (int g = 0; g < 3; ++g) {
      const size_t rrow = (size_t)(g * 1024 + g0 + srow);
      if (PLANES) {
        size_t ob = rrow * 1024 + sk4;
        stu4(&sBh[g * 1280 + sidx], ldu4(&whhh[ob]));
        stu4(&sBl[g * 1280 + sidx], ldu4(&whhl[ob]));
      } else {
        float4 w4 = *(const float4*)&whh[rrow * 1024 + sk4];
        u16 h0,l0,h1,l1,h2,l2,h3,l3;
        split2(w4.x,h0,l0); split2(w4.y,h1,l1); split2(w4.z,h2,l2); split2(w4.w,h3,l3);
        stu4(&sBh[g * 1280 + sidx], make_ushort4(h0,h1,h2,h3));
        stu4(&sBl[g * 1280 + sidx], make_ushort4(l0,l1,l2,l3));
      }
    }
  }
  __syncthreads();
  for (int it = 0; it < 32; ++it) {
    const int db = it & 1, nb = db ^ 1;
    const bool pf = (it + 1 < 32);
    ushort4 nah, nal, nb0h, nb0l, nb1h, nb1l, nb2h, nb2l;
    if (pf) {
      const int k0 = (it + 1) << 5;
      size_t oa = (size_t)(m0 + srow) * HID + k0 + sk4;
      nah = ldu4c(&chi[oa]); nal = ldu4c(&clo[oa]);
      if (PLANES) {
        size_t r0 = (size_t)(0 * 1024 + g0 + srow) * 1024 + k0 + sk4;
        size_t r1 = (size_t)(1 * 1024 + g0 + srow) * 1024 + k0 + sk4;
        size_t r2 = (size_t)(2 * 1024 + g0 + srow) * 1024 + k0 + sk4;
        nb0h = ldu4(&whhh[r0]); nb0l = ldu4(&whhl[r0]);
        nb1h = ldu4(&whhh[r1]); nb1l = ldu4(&whhl[r1]);
        nb2h = ldu4(&whhh[r2]); nb2l = ldu4(&whhl[r2]);
      } else {
        #pragma unroll
        for (int g = 0; g < 3; ++g) {
          float4 w4 = *(const float4*)&whh[(size_t)(g * 1024 + g0 + srow) * 1024 + k0 + sk4];
          u16 h0,l0,h1,l1,h2,l2,h3,l3;
          split2(w4.x,h0,l0); split2(w4.y,h1,l1); split2(w4.z,h2,l2); split2(w4.w,h3,l3);
          ushort4 hh = make_ushort4(h0,h1,h2,h3), ll = make_ushort4(l0,l1,l2,l3);
          if (g == 0) { nb0h = hh; nb0l = ll; }
          else if (g == 1) { nb1h = hh; nb1l = ll; }
          else { nb2h = hh; nb2l = ll; }
        }
      }
    }
    const int fa = db * 1280 + (wm + lr) * 40 + lq * 8;
    s16x8 ah = *(const s16x8*)&sAh[fa];
    s16x8 al = *(const s16x8*)&sAl[fa];
    #pragma unroll
    for (int g = 0; g < 3; ++g) {
      const int fb = db * 3840 + g * 1280 + (wn + lr) * 40 + lq * 8;
      s16x8 bh = *(const s16x8*)&sBh[fb];
      s16x8 bl = *(const s16x8*)&sBl[fb];
      f32x4 c = (g == 0) ? aR : (g == 1) ? aZ : aNh;
      c = mfma16(ah, bh, c); c = mfma16(ah, bl, c); c = mfma16(al, bh, c);
      if (g == 0) aR = c; else if (g == 1) aZ = c; else aNh = c;
    }
    if (pf) {
      stu4(&sAh[nb * 1280 + sidx], nah); stu4(&sAl[nb * 1280 + sidx], nal);
      stu4(&sBh[nb * 3840 + 0 * 1280 + sidx], nb0h); stu4(&sBl[nb * 3840 + 0 * 1280 + sidx], nb0l);
      stu4(&sBh[nb * 3840 + 1 * 1280 + sidx], nb1h); stu4(&sBl[nb * 3840 + 1 * 1280 + sidx], nb1l);
      stu4(&sBh[nb * 3840 + 2 * 1280 + sidx], nb2h); stu4(&sBl[nb * 3840 + 2 * 1280 + sidx], nb2l);
    }
    __syncthreads();
  }
  // phase 1: gi (x_t split on the fly), K = 256
  {
    const float* xp = &data[(size_t)(t * BATCH + m0 + srow) * ROWSTRIDE + sk4];
    u16 xh[4], xl[4];
    #pragma unroll
    for (int i = 0; i < 4; i++) split2(xp[i], xh[i], xl[i]);
    stu4(&sAh[sidx], make_ushort4(xh[0], xh[1], xh[2], xh[3]));
    stu4(&sAl[sidx], make_ushort4(xl[0], xl[1], xl[2], xl[3]));
    #pragma unroll
    for (int g = 0; g < 3; ++g) {
      const size_t rrow = (size_t)(g * 1024 + g0 + srow);
      if (PLANES) {
        size_t ob = rrow * 256 + sk4;
        stu4(&sBh[g * 1280 + sidx], ldu4(&wihh[ob]));
        stu4(&sBl[g * 1280 + sidx], ldu4(&wihl[ob]));
      } else {
        float4 w4 = *(const float4*)&wih[rrow * 256 + sk4];
        u16 h0,l0,h1,l1,h2,l2,h3,l3;
        split2(w4.x,h0,l0); split2(w4.y,h1,l1); split2(w4.z,h2,l2); split2(w4.w,h3,l3);
        stu4(&sBh[g * 1280 + sidx], make_ushort4(h0,h1,h2,h3));
        stu4(&sBl[g * 1280 + sidx], make_ushort4(l0,l1,l2,l3));
      }
    }
  }
  __syncthreads();
  for (int it = 0; it < 8; ++it) {
    const int db = it & 1, nb = db ^ 1;
    const bool pf = (it + 1 < 8);
    ushort4 nah, nal, nb0h, nb0l, nb1h, nb1l, nb2h, nb2l;
    if (pf) {
      const int k0 = (it + 1) << 5;
      const float* xp = &data[(size_t)(t * BATCH + m0 + srow) * ROWSTRIDE + k0 + sk4];
      u16 xh[4], xl[4];
      #pragma unroll
      for (int i = 0; i < 4; i++) split2(xp[i], xh[i], xl[i]);
      nah = make_ushort4(xh[0], xh[1], xh[2], xh[3]);
      nal = make_ushort4(xl[0], xl[1], xl[2], xl[3]);
      if (PLANES) {
        size_t r0 = (size_t)(0 * 1024 + g0 + srow) * 256 + k0 + sk4;
        size_t r1 = (size_t)(1 * 1024 + g0 + srow) * 256 + k0 + sk4;
        size_t r2 = (size_t)(2 * 1024 + g0 + srow) * 256 + k0 + sk4;
        nb0h = ldu4(&wihh[r0]); nb0l = ldu4(&wihl[r0]);
        nb1h = ldu4(&wihh[r1]); nb1l = ldu4(&wihl[r1]);
        nb2h = ldu4(&wihh[r2]); nb2l = ldu4(&wihl[r2]);
      } else {
        #pragma unroll
        for (int g = 0; g < 3; ++g) {
          float4 w4 = *(const float4*)&wih[(size_t)(g * 1024 + g0 + srow) * 256 + k0 + sk4];
          u16 h0,l0,h1,l1,h2,l2,h3,l3;
          split2(w4.x,h0,l0); split2(w4.y,h1,l1); split2(w4.z,h2,l2); split2(w4.w,h3,l3);
          ushort4 hh = make_ushort4(h0,h1,h2,h3), ll = make_ushort4(l0,l1,l2,l3);
          if (g == 0) { nb0h = hh; nb0l = ll; }
          else if (g == 1) { nb1h = hh; nb1l = ll; }
          else { nb2h = hh; nb2l = ll; }
        }
      }
    }
    const int fa = db * 1280 + (wm + lr) * 40 + lq * 8;
    s16x8 ah = *(const s16x8*)&sAh[fa];
    s16x8 al = *(const s16x8*)&sAl[fa];
    #pragma unroll
    for (int g = 0; g < 3; ++g) {
      const int fb = db * 3840 + g * 1280 + (wn + lr) * 40 + lq * 8;
      s16x8 bh = *(const s16x8*)&sBh[fb];
      s16x8 bl = *(const s16x8*)&sBl[fb];
      f32x4 c = (g == 0) ? aR : (g == 1) ? aZ : aNi;
      c = mfma16(ah, bh, c); c = mfma16(ah, bl, c); c = mfma16(al, bh, c);
      if (g == 0) aR = c; else if (g == 1) aZ = c; else aNi = c;
    }
    if (pf) {
      stu4(&sAh[nb * 1280 + sidx], nah); stu4(&sAl[nb * 1280 + sidx], nal);
      stu4(&sBh[nb * 3840 + 0 * 1280 + sidx], nb0h); stu4(&sBl[nb * 3840 + 0 * 1280 + sidx], nb0l);
      stu4(&sBh[nb * 3840 + 1 * 1280 + sidx], nb1h); stu4(&sBl[nb * 3840 + 1 * 1280 + sidx], nb1l);
      stu4(&sBh[nb * 3840 + 2 * 1280 + sidx], nb2h); stu4(&sBl[nb * 3840 + 2 * 1280 + sidx], nb2l);
    }
    __syncthreads();
  }
  // epilogue: pointwise GRU + outputs + next state
  #pragma unroll
  for (int r = 0; r < 4; ++r) {
    const int row = m0 + wm + lq * 4 + r;
    const int jg = g0 + wn + lr;
    float rr = sigmoidf_(aR[r] + bih[jg] + bhh[jg]);
    float zz = sigmoidf_(aZ[r] + bih[1024 + jg] + bhh[1024 + jg]);
    float nn = tanhf(aNi[r] + bih[2048 + jg] + rr * (aNh[r] + bhh[2048 + jg]));
    size_t oh = (size_t)row * HID + jg;
    float hv = p2f(ldu16c(&chi[oh]), ldu16c(&clo[oh]));
    float val = (1.f - zz) * nn + zz * hv;
    out[(size_t)LSEQ * BATCH * LAT + oh] = val;        // output 1 (new_h)
    if (jg < LAT) {
      out[((size_t)t * BATCH + row) * LAT + jg] = val; // output 0
      u16 h, l; split2(val, h, l);
      stu16c(&nhi[oh], h); stu16c(&nhi[oh + LAT], h);
      stu16c(&nlo[oh], l); stu16c(&nlo[oh + LAT], l);
    }
  }
}

// ---------- one persistent kernel, 8 independent batch-row slices ----------
template<bool PLANES>
__global__ __launch_bounds__(256, 1) void fused_seq_k(
    const u16* __restrict__ w1h, const u16* __restrict__ w1l,
    const u16* __restrict__ w2h, const u16* __restrict__ w2l,
    const float* __restrict__ b1, const float* __restrict__ b2,
    u16* __restrict__ c0h, u16* __restrict__ c0l,
    u16* __restrict__ c1h, u16* __restrict__ c1l,
    u16* __restrict__ h1h, u16* __restrict__ h1l,
    const float* __restrict__ whh, const u16* __restrict__ whhh, const u16* __restrict__ whhl,
    const float* __restrict__ wih, const u16* __restrict__ wihh, const u16* __restrict__ wihl,
    const float* __restrict__ bih, const float* __restrict__ bhh,
    const float* __restrict__ data, float* __restrict__ out,
    unsigned* __restrict__ bar)
{
  __shared__ u16 pool[20480];   // 40 KB, carved per phase
  const int b = blockIdx.x;
  const int tid = threadIdx.x;
  const int slice = b >> 5;          // constant across all phases: rows [32*slice, 32*slice+32)
  const int l = b & 31;              // local id within slice
  const int m0 = slice << 5;
  unsigned* line = bar + slice * 64; // one cacheline per slice
  unsigned rnd = 0;

  for (int t = 0; t < LSEQ; ++t) {
    u16* chi = (t & 1) ? c1h : c0h;
    u16* clo = (t & 1) ? c1l : c0l;
    u16* nhi = (t & 1) ? c0h : c1h;
    u16* nlo = (t & 1) ? c0l : c1l;
    for (int s = 0; s < 3; ++s) {
      {  // mlp1: per slice, 32 n-tiles of 32 -> h1 = tanh(y @ w1 + b1)
        const int n0 = l << 5;
        gemm_phase<1>(pool, pool + 2560, 1280, pool + 5120, pool + 7680, 1280,
                      chi, clo, HID, m0, w1h, w1l, 512, n0, 512,
                      b1, h1h, h1l, data, t, tid);
      }
      ++rnd; slice_barrier(line, rnd);
      if (l < 16) {  // mlp2: per slice, 16 n-tiles of 32 -> y += (h1 @ w2 + b2)*dt/3
        const int n0 = l << 5;
        gemm_phase<2>(pool, pool + 2560, 1280, pool + 5120, pool + 7680, 1280,
                      h1h, h1l, HID, m0, w2h, w2l, 1024, n0, 1024,
                      b2, chi, clo, data, t, tid);
      }
      ++rnd; slice_barrier(line, rnd);
    }
    gru_phase<PLANES>(pool, chi, clo, whh, whhh, whhl, wih, wihh, wihl,
                      bih, bhh, data, t, nhi, nlo, out, l << 5, m0, tid);
    if (t + 1 < LSEQ) { ++rnd; slice_barrier(line, rnd); }
  }
}

extern "C" void kernel_launch(void* const* d_in, const int* in_sizes, int n_in,
                              void* d_out, int out_size, void* d_ws, size_t ws_size,
                              hipStream_t stream)
{
  const float* data = (const float*)d_in[0];
  const float* w1   = (const float*)d_in[1];
  const float* b1   = (const float*)d_in[2];
  const float* w2   = (const float*)d_in[3];
  const float* b2   = (const float*)d_in[4];
  const float* wih  = (const float*)d_in[5];
  const float* bih  = (const float*)d_in[6];
  const float* whh  = (const float*)d_in[7];
  const float* bhh  = (const float*)d_in[8];
  float* out = (float*)d_out;

  char* w = (char*)d_ws;
  auto alloc = [&](size_t bytes) { char* p = w; w += bytes; return p; };
  u16* w1h = (u16*)alloc((size_t)512 * 1024 * 2);   // [1024 n][512 k] planes
  u16* w1l = (u16*)alloc((size_t)512 * 1024 * 2);
  u16* w2h = (u16*)alloc((size_t)512 * 1024 * 2);   // [512 n][1024 k] planes
  u16* w2l = (u16*)alloc((size_t)512 * 1024 * 2);
  u16* c0h = (u16*)alloc((size_t)BATCH * HID * 2);
  u16* c0l = (u16*)alloc((size_t)BATCH * HID * 2);
  u16* c1h = (u16*)alloc((size_t)BATCH * HID * 2);
  u16* c1l = (u16*)alloc((size_t)BATCH * HID * 2);
  u16* h1h = (u16*)alloc((size_t)BATCH * HID * 2);
  u16* h1l = (u16*)alloc((size_t)BATCH * HID * 2);
  unsigned* bar = (unsigned*)alloc(4096);            // 16 counter lines, 256B apart
  size_t base = (size_t)(w - (char*)d_ws);
  size_t need_opt = base + 2 * ((size_t)3072 * 1024 * 2) + 2 * ((size_t)3072 * 256 * 2);
  bool planes = ws_size >= need_opt;
  u16 *whhh = nullptr, *whhl = nullptr, *wihh = nullptr, *wihl = nullptr;
  if (planes) {
    whhh = (u16*)alloc((size_t)3072 * 1024 * 2);
    whhl = (u16*)alloc((size_t)3072 * 1024 * 2);
    wihh = (u16*)alloc((size_t)3072 * 256 * 2);
    wihl = (u16*)alloc((size_t)3072 * 256 * 2);
  }

  tsplit_k<<<dim3(512 / 32, 1024 / 32), 256, 0, stream>>>(w1, w1h, w1l, 512, 1024);
  tsplit_k<<<dim3(1024 / 32, 512 / 32), 256, 0, stream>>>(w2, w2h, w2l, 1024, 512);
  if (planes) {
    esplit_k<<<dim3((3072 * 1024) / 1024), 256, 0, stream>>>(whh, whhh, whhl);
    esplit_k<<<dim3((3072 * 256) / 1024), 256, 0, stream>>>(wih, wihh, wihl);
  }
  init_k<<<dim3(256), 256, 0, stream>>>(c0h, c0l, bar);

  if (planes) {
    fused_seq_k<true><<<dim3(NBLK), dim3(256), 0, stream>>>(
        w1h, w1l, w2h, w2l, b1, b2, c0h, c0l, c1h, c1l, h1h, h1l,
        whh, whhh, whhl, wih, wihh, wihl, bih, bhh, data, out, bar);
  } else {
    fused_seq_k<false><<<dim3(NBLK), dim3(256), 0, stream>>>(
        w1h, w1l, w2h, w2l, b1, b2, c0h, c0l, c1h, c1l, h1h, h1l,
        whh, whhh, whhl, wih, wihh, wihl, bih, bhh, data, out, bar);
  }
}

// Round 7
// 3920.782 us; speedup vs baseline: 5.3405x; 1.5319x over previous
//
#include <hip/hip_runtime.h>

#define LSEQ 50
#define BATCH 256
#define DIN 256
#define LAT 512
#define HID 1024
#define ROWSTRIDE 257  // D_IN + 1 (dt channel)
#define NBLK 256

typedef __attribute__((ext_vector_type(8))) short s16x8;
typedef __attribute__((ext_vector_type(4))) float f32x4;
using u16 = unsigned short;
using u64 = unsigned long long;

__device__ __forceinline__ u16 bfhi(float v) {
  union { float f; unsigned u; } a; a.f = v;
  return (u16)((a.u + 0x7FFFu + ((a.u >> 16) & 1u)) >> 16);
}
__device__ __forceinline__ void split2(float v, u16& h, u16& l) {
  u16 hu = bfhi(v);
  union { unsigned u; float f; } hf; hf.u = ((unsigned)hu) << 16;
  h = hu; l = bfhi(v - hf.f);
}
__device__ __forceinline__ float p2f(u16 h, u16 l) {
  union { unsigned u; float f; } a, b;
  a.u = ((unsigned)h) << 16; b.u = ((unsigned)l) << 16;
  return a.f + b.f;
}
__device__ __forceinline__ float sigmoidf_(float x) { return 1.f / (1.f + __expf(-x)); }
__device__ __forceinline__ f32x4 mfma16(s16x8 a, s16x8 b, f32x4 c) {
  return __builtin_amdgcn_mfma_f32_16x16x32_bf16(a, b, c, 0, 0, 0);
}
__device__ __forceinline__ ushort4 ldu4(const u16* p) { return *(const ushort4*)p; }
__device__ __forceinline__ void stu4(u16* p, ushort4 v) { *(ushort4*)p = v; }

// ---------- coherent (LLC-authoritative) accessors for cross-block state ----------
__device__ __forceinline__ ushort4 ldu4c(const u16* p) {
  u64 v = __hip_atomic_load((const u64*)p, __ATOMIC_RELAXED, __HIP_MEMORY_SCOPE_AGENT);
  union { u64 q; ushort4 s; } u; u.q = v; return u.s;
}
__device__ __forceinline__ u16 ldu16c(const u16* p) {
  return __hip_atomic_load(p, __ATOMIC_RELAXED, __HIP_MEMORY_SCOPE_AGENT);
}
__device__ __forceinline__ void stu16c(u16* p, u16 v) {
  __hip_atomic_store(p, v, __ATOMIC_RELAXED, __HIP_MEMORY_SCOPE_AGENT);
}

// ---------- slice barrier (round-6 verbatim) ----------
__device__ __forceinline__ void slice_barrier(unsigned* line, unsigned k) {
  asm volatile("s_waitcnt vmcnt(0)" ::: "memory");
  __syncthreads();
  if (threadIdx.x == 0) {
    __hip_atomic_fetch_add(line, 1u, __ATOMIC_RELAXED, __HIP_MEMORY_SCOPE_AGENT);
    const unsigned tgt = k * 32u;
    while (__hip_atomic_load(line, __ATOMIC_RELAXED, __HIP_MEMORY_SCOPE_AGENT) < tgt) {
      __builtin_amdgcn_s_sleep(1);
    }
  }
  __syncthreads();
}

// ---------- preprocessing (unchanged) ----------
__global__ __launch_bounds__(256) void tsplit_k(const float* __restrict__ W,
    u16* __restrict__ Thi, u16* __restrict__ Tlo, int K, int N)
{
  __shared__ unsigned Ts[32][33];
  const int bk = blockIdx.x * 32, bn = blockIdx.y * 32;
  const int t = threadIdx.x;
  const int n_l = t & 31, k_l4 = (t >> 5) * 4;
  #pragma unroll
  for (int i = 0; i < 4; i++) {
    float v = W[(size_t)(bk + k_l4 + i) * N + bn + n_l];
    u16 h, l; split2(v, h, l);
    Ts[k_l4 + i][n_l] = ((unsigned)h << 16) | l;
  }
  __syncthreads();
  const int k_l = t & 31, n_l2 = t >> 5;
  #pragma unroll
  for (int i = 0; i < 4; i++) {
    int nn = n_l2 + 8 * i;
    unsigned u = Ts[k_l][nn];
    size_t o = (size_t)(bn + nn) * K + bk + k_l;
    Thi[o] = (u16)(u >> 16);
    Tlo[o] = (u16)(u & 0xFFFFu);
  }
}

__global__ __launch_bounds__(256) void esplit_k(const float* __restrict__ W,
    u16* __restrict__ Phi, u16* __restrict__ Plo)
{
  size_t i4 = ((size_t)blockIdx.x * 256 + threadIdx.x) * 4;
  float4 v = *(const float4*)&W[i4];
  u16 h[4], l[4];
  split2(v.x, h[0], l[0]); split2(v.y, h[1], l[1]);
  split2(v.z, h[2], l[2]); split2(v.w, h[3], l[3]);
  *(ushort4*)&Phi[i4] = make_ushort4(h[0], h[1], h[2], h[3]);
  *(ushort4*)&Plo[i4] = make_ushort4(l[0], l[1], l[2], l[3]);
}

__global__ __launch_bounds__(256) void init_k(u16* __restrict__ c0h, u16* __restrict__ c0l,
                                              unsigned* __restrict__ bar)
{
  size_t i4 = ((size_t)blockIdx.x * 256 + threadIdx.x) * 4;
  *(ushort4*)&c0h[i4] = make_ushort4(0, 0, 0, 0);
  *(ushort4*)&c0l[i4] = make_ushort4(0, 0, 0, 0);
  if (blockIdx.x == 0 && threadIdx.x < 16) bar[threadIdx.x * 64] = 0u;
}

// ---------- gemm phase: U=4 pipelined (8 LDS slots, 1 sync per 4 K-tiles) ----------
// A = state (coherent loads), B = weights (plain loads).
// EPI 1: O = split(tanh(acc+bias));  EPI 2: y = p2f(O) + (acc+bias)*dt/3; O = split(y)
template<int EPI, int NITER>
__device__ __forceinline__ void gemm_phase(
    u16* __restrict__ Sah, u16* __restrict__ Sal,
    u16* __restrict__ Sbh, u16* __restrict__ Sbl,
    const u16* __restrict__ Ahi, const u16* __restrict__ Alo, int ldA, int m0,
    const u16* __restrict__ Bhi, const u16* __restrict__ Blo, int ldB, int n0,
    const float* __restrict__ bias,
    u16* __restrict__ Ohi, u16* __restrict__ Olo,
    const float* __restrict__ data, int t, int tid)
{
  const int lane = tid & 63, wave = tid >> 6;
  const int wm = (wave >> 1) << 4, wn = (wave & 1) << 4;
  const int lr = lane & 15, lq = lane >> 4;
  const int srow = tid >> 3, sk4 = (tid & 7) << 2;
  const int sidx = srow * 40 + sk4;
  const size_t rowA = (size_t)(m0 + srow) * ldA + sk4;
  const size_t rowB = (size_t)(n0 + srow) * ldB + sk4;
  f32x4 acc = {0.f, 0.f, 0.f, 0.f};
  ushort4 rah[4], ral[4], rbh[4], rbl[4];
  // prologue: tiles 0..3 -> slots 0..3
  #pragma unroll
  for (int d = 0; d < 4; ++d) {
    const int k0 = d << 5;
    rah[d] = ldu4c(&Ahi[rowA + k0]); ral[d] = ldu4c(&Alo[rowA + k0]);
    rbh[d] = ldu4(&Bhi[rowB + k0]);  rbl[d] = ldu4(&Blo[rowB + k0]);
  }
  #pragma unroll
  for (int d = 0; d < 4; ++d) {
    stu4(&Sah[d * 1280 + sidx], rah[d]); stu4(&Sal[d * 1280 + sidx], ral[d]);
    stu4(&Sbh[d * 1280 + sidx], rbh[d]); stu4(&Sbl[d * 1280 + sidx], rbl[d]);
  }
  __syncthreads();
  constexpr int NSEG = NITER / 4;
  for (int p = 0; p < NSEG; ++p) {
    const int rb = (p & 1) * 5120;     // 4-slot group being read
    const int wb = 5120 - rb;          // 4-slot group being filled
    const bool pf = (p + 1 < NSEG);
    if (pf) {
      #pragma unroll
      for (int d = 0; d < 4; ++d) {
        const int k0 = (((p + 1) << 2) + d) << 5;
        rah[d] = ldu4c(&Ahi[rowA + k0]); ral[d] = ldu4c(&Alo[rowA + k0]);
        rbh[d] = ldu4(&Bhi[rowB + k0]);  rbl[d] = ldu4(&Blo[rowB + k0]);
      }
    }
    #pragma unroll
    for (int d = 0; d < 4; ++d) {
      const int fa = rb + d * 1280 + (wm + lr) * 40 + lq * 8;
      const int fb = rb + d * 1280 + (wn + lr) * 40 + lq * 8;
      s16x8 ah = *(const s16x8*)&Sah[fa];
      s16x8 al = *(const s16x8*)&Sal[fa];
      s16x8 bh = *(const s16x8*)&Sbh[fb];
      s16x8 bl = *(const s16x8*)&Sbl[fb];
      acc = mfma16(ah, bh, acc);
      acc = mfma16(ah, bl, acc);
      acc = mfma16(al, bh, acc);
    }
    if (pf) {
      #pragma unroll
      for (int d = 0; d < 4; ++d) {
        stu4(&Sah[wb + d * 1280 + sidx], rah[d]); stu4(&Sal[wb + d * 1280 + sidx], ral[d]);
        stu4(&Sbh[wb + d * 1280 + sidx], rbh[d]); stu4(&Sbl[wb + d * 1280 + sidx], rbl[d]);
      }
    }
    __syncthreads();
  }
  #pragma unroll
  for (int r = 0; r < 4; ++r) {
    const int row = m0 + wm + lq * 4 + r;
    const int col = n0 + wn + lr;
    float v = acc[r] + bias[col];
    size_t o = (size_t)row * HID + col;
    if (EPI == 1) {
      float h1 = tanhf(v);
      u16 h, l; split2(h1, h, l);
      stu16c(&Ohi[o], h); stu16c(&Olo[o], l);
    } else {
      float dt3 = data[(size_t)(t * BATCH + row) * ROWSTRIDE + DIN] * (1.f / 3.f);
      float y = p2f(ldu16c(&Ohi[o]), ldu16c(&Olo[o])) + v * dt3;
      u16 h, l; split2(y, h, l);
      stu16c(&Ohi[o], h); stu16c(&Olo[o], l);
    }
  }
}

// ---------- fused GRU phase: U=2 pipelined (4 LDS slots, 1 sync per 2 K-tiles) ----------
template<bool PLANES>
__device__ __forceinline__ void gru_phase(
    u16* pool,
    const u16* __restrict__ chi, const u16* __restrict__ clo,
    const float* __restrict__ whh, const u16* __restrict__ whhh, const u16* __restrict__ whhl,
    const float* __restrict__ wih, const u16* __restrict__ wihh, const u16* __restrict__ wihl,
    const float* __restrict__ bih, const float* __restrict__ bhh,
    const float* __restrict__ data, int t,
    u16* __restrict__ nhi, u16* __restrict__ nlo,
    float* __restrict__ out, int g0, int m0, int tid)
{
  u16* sAh = pool;              // 4 slots * 1280
  u16* sAl = pool + 5120;
  u16* sBh = pool + 10240;      // 4 slots * 3840
  u16* sBl = pool + 25600;
  const int lane = tid & 63, wave = tid >> 6;
  const int wm = (wave >> 1) << 4, wn = (wave & 1) << 4;
  const int lr = lane & 15, lq = lane >> 4;
  const int srow = tid >> 3, sk4 = (tid & 7) << 2;
  const int sidx = srow * 40 + sk4;
  f32x4 aR = {0,0,0,0}, aZ = {0,0,0,0}, aNh = {0,0,0,0}, aNi = {0,0,0,0};

  ushort4 rah[2], ral[2], rbh[2][3], rbl[2][3];
  float4  rbf[2][3];
  float   rxf[2][4];

  // ===== phase 0: gh (K=1024 over chi/whh), 32 tiles =====
  {
    const size_t rowA = (size_t)(m0 + srow) * HID + sk4;
    // prologue: tiles 0,1 -> slots 0,1
    #pragma unroll
    for (int j = 0; j < 2; ++j) {
      const int k0 = j << 5;
      rah[j] = ldu4c(&chi[rowA + k0]); ral[j] = ldu4c(&clo[rowA + k0]);
      #pragma unroll
      for (int g = 0; g < 3; ++g) {
        const size_t rr = (size_t)(g * 1024 + g0 + srow) * 1024 + k0 + sk4;
        if (PLANES) { rbh[j][g] = ldu4(&whhh[rr]); rbl[j][g] = ldu4(&whhl[rr]); }
        else rbf[j][g] = *(const float4*)&whh[rr];
      }
    }
    #pragma unroll
    for (int j = 0; j < 2; ++j) {
      stu4(&sAh[j * 1280 + sidx], rah[j]); stu4(&sAl[j * 1280 + sidx], ral[j]);
      #pragma unroll
      for (int g = 0; g < 3; ++g) {
        if (PLANES) {
          stu4(&sBh[j * 3840 + g * 1280 + sidx], rbh[j][g]);
          stu4(&sBl[j * 3840 + g * 1280 + sidx], rbl[j][g]);
        } else {
          float4 w4 = rbf[j][g];
          u16 h0,l0,h1,l1,h2,l2,h3,l3;
          split2(w4.x,h0,l0); split2(w4.y,h1,l1); split2(w4.z,h2,l2); split2(w4.w,h3,l3);
          stu4(&sBh[j * 3840 + g * 1280 + sidx], make_ushort4(h0,h1,h2,h3));
          stu4(&sBl[j * 3840 + g * 1280 + sidx], make_ushort4(l0,l1,l2,l3));
        }
      }
    }
    __syncthreads();
    for (int p = 0; p < 16; ++p) {
      const int rb = (p & 1) * 2;        // slot index base
      const int wb = 2 - rb;
      const bool pf = (p + 1 < 16);
      if (pf) {
        #pragma unroll
        for (int j = 0; j < 2; ++j) {
          const int k0 = (((p + 1) << 1) + j) << 5;
          rah[j] = ldu4c(&chi[rowA + k0]); ral[j] = ldu4c(&clo[rowA + k0]);
          #pragma unroll
          for (int g = 0; g < 3; ++g) {
            const size_t rr = (size_t)(g * 1024 + g0 + srow) * 1024 + k0 + sk4;
            if (PLANES) { rbh[j][g] = ldu4(&whhh[rr]); rbl[j][g] = ldu4(&whhl[rr]); }
            else rbf[j][g] = *(const float4*)&whh[rr];
          }
        }
      }
      #pragma unroll
      for (int j = 0; j < 2; ++j) {
        const int sa = (rb + j) * 1280 + (wm + lr) * 40 + lq * 8;
        const int sb = (rb + j) * 3840 + (wn + lr) * 40 + lq * 8;
        s16x8 ah = *(const s16x8*)&sAh[sa];
        s16x8 al = *(const s16x8*)&sAl[sa];
        #pragma unroll
        for (int g = 0; g < 3; ++g) {
          s16x8 bh = *(const s16x8*)&sBh[sb + g * 1280];
          s16x8 bl = *(const s16x8*)&sBl[sb + g * 1280];
          f32x4 c = (g == 0) ? aR : (g == 1) ? aZ : aNh;
          c = mfma16(ah, bh, c); c = mfma16(ah, bl, c); c = mfma16(al, bh, c);
          if (g == 0) aR = c; else if (g == 1) aZ = c; else aNh = c;
        }
      }
      if (pf) {
        #pragma unroll
        for (int j = 0; j < 2; ++j) {
          stu4(&sAh[(wb + j) * 1280 + sidx], rah[j]); stu4(&sAl[(wb + j) * 1280 + sidx], ral[j]);
          #pragma unroll
          for (int g = 0; g < 3; ++g) {
            if (PLANES) {
              stu4(&sBh[(wb + j) * 3840 + g * 1280 + sidx], rbh[j][g]);
              stu4(&sBl[(wb + j) * 3840 + g * 1280 + sidx], rbl[j][g]);
            } else {
              float4 w4 = rbf[j][g];
              u16 h0,l0,h1,l1,h2,l2,h3,l3;
              split2(w4.x,h0,l0); split2(w4.y,h1,l1); split2(w4.z,h2,l2); split2(w4.w,h3,l3);
              stu4(&sBh[(wb + j) * 3840 + g * 1280 + sidx], make_ushort4(h0,h1,h2,h3));
              stu4(&sBl[(wb + j) * 3840 + g * 1280 + sidx], make_ushort4(l0,l1,l2,l3));
            }
          }
        }
      }
      __syncthreads();
    }
  }

  // ===== phase 1: gi (K=256 over x_t/wih), 8 tiles =====
  {
    const size_t rowX = (size_t)(t * BATCH + m0 + srow) * ROWSTRIDE + sk4;
    // prologue: tiles 0,1 -> slots 0,1
    #pragma unroll
    for (int j = 0; j < 2; ++j) {
      const int k0 = j << 5;
      #pragma unroll
      for (int i = 0; i < 4; ++i) rxf[j][i] = data[rowX + k0 + i];
      #pragma unroll
      for (int g = 0; g < 3; ++g) {
        const size_t rr = (size_t)(g * 1024 + g0 + srow) * 256 + k0 + sk4;
        if (PLANES) { rbh[j][g] = ldu4(&wihh[rr]); rbl[j][g] = ldu4(&wihl[rr]); }
        else rbf[j][g] = *(const float4*)&wih[rr];
      }
    }
    #pragma unroll
    for (int j = 0; j < 2; ++j) {
      u16 xh[4], xl[4];
      #pragma unroll
      for (int i = 0; i < 4; ++i) split2(rxf[j][i], xh[i], xl[i]);
      stu4(&sAh[j * 1280 + sidx], make_ushort4(xh[0], xh[1], xh[2], xh[3]));
      stu4(&sAl[j * 1280 + sidx], make_ushort4(xl[0], xl[1], xl[2], xl[3]));
      #pragma unroll
      for (int g = 0; g < 3; ++g) {
        if (PLANES) {
          stu4(&sBh[j * 3840 + g * 1280 + sidx], rbh[j][g]);
          stu4(&sBl[j * 3840 + g * 1280 + sidx], rbl[j][g]);
        } else {
          float4 w4 = rbf[j][g];
          u16 h0,l0,h1,l1,h2,l2,h3,l3;
          split2(w4.x,h0,l0); split2(w4.y,h1,l1); split2(w4.z,h2,l2); split2(w4.w,h3,l3);
          stu4(&sBh[j * 3840 + g * 1280 + sidx], make_ushort4(h0,h1,h2,h3));
          stu4(&sBl[j * 3840 + g * 1280 + sidx], make_ushort4(l0,l1,l2,l3));
        }
      }
    }
    __syncthreads();
    for (int p = 0; p < 4; ++p) {
      const int rb = (p & 1) * 2;
      const int wb = 2 - rb;
      const bool pf = (p + 1 < 4);
      if (pf) {
        #pragma unroll
        for (int j = 0; j < 2; ++j) {
          const int k0 = (((p + 1) << 1) + j) << 5;
          #pragma unroll
          for (int i = 0; i < 4; ++i) rxf[j][i] = data[rowX + k0 + i];
          #pragma unroll
          for (int g = 0; g < 3; ++g) {
            const size_t rr = (size_t)(g * 1024 + g0 + srow) * 256 + k0 + sk4;
            if (PLANES) { rbh[j][g] = ldu4(&wihh[rr]); rbl[j][g] = ldu4(&wihl[rr]); }
            else rbf[j][g] = *(const float4*)&wih[rr];
          }
        }
      }
      #pragma unroll
      for (int j = 0; j < 2; ++j) {
        const int sa = (rb + j) * 1280 + (wm + lr) * 40 + lq * 8;
        const int sb = (rb + j) * 3840 + (wn + lr) * 40 + lq * 8;
        s16x8 ah = *(const s16x8*)&sAh[sa];
        s16x8 al = *(const s16x8*)&sAl[sa];
        #pragma unroll
        for (int g = 0; g < 3; ++g) {
          s16x8 bh = *(const s16x8*)&sBh[sb + g * 1280];
          s16x8 bl = *(const s16x8*)&sBl[sb + g * 1280];
          f32x4 c = (g == 0) ? aR : (g == 1) ? aZ : aNi;
          c = mfma16(ah, bh, c); c = mfma16(ah, bl, c); c = mfma16(al, bh, c);
          if (g == 0) aR = c; else if (g == 1) aZ = c; else aNi = c;
        }
      }
      if (pf) {
        #pragma unroll
        for (int j = 0; j < 2; ++j) {
          u16 xh[4], xl[4];
          #pragma unroll
          for (int i = 0; i < 4; ++i) split2(rxf[j][i], xh[i], xl[i]);
          stu4(&sAh[(wb + j) * 1280 + sidx], make_ushort4(xh[0], xh[1], xh[2], xh[3]));
          stu4(&sAl[(wb + j) * 1280 + sidx], make_ushort4(xl[0], xl[1], xl[2], xl[3]));
          #pragma unroll
          for (int g = 0; g < 3; ++g) {
            if (PLANES) {
              stu4(&sBh[(wb + j) * 3840 + g * 1280 + sidx], rbh[j][g]);
              stu4(&sBl[(wb + j) * 3840 + g * 1280 + sidx], rbl[j][g]);
            } else {
              float4 w4 = rbf[j][g];
              u16 h0,l0,h1,l1,h2,l2,h3,l3;
              split2(w4.x,h0,l0); split2(w4.y,h1,l1); split2(w4.z,h2,l2); split2(w4.w,h3,l3);
              stu4(&sBh[(wb + j) * 3840 + g * 1280 + sidx], make_ushort4(h0,h1,h2,h3));
              stu4(&sBl[(wb + j) * 3840 + g * 1280 + sidx], make_ushort4(l0,l1,l2,l3));
            }
          }
        }
      }
      __syncthreads();
    }
  }

  // ===== epilogue: pointwise GRU + outputs + next state =====
  #pragma unroll
  for (int r = 0; r < 4; ++r) {
    const int row = m0 + wm + lq * 4 + r;
    const int jg = g0 + wn + lr;
    float rr = sigmoidf_(aR[r] + bih[jg] + bhh[jg]);
    float zz = sigmoidf_(aZ[r] + bih[1024 + jg] + bhh[1024 + jg]);
    float nn = tanhf(aNi[r] + bih[2048 + jg] + rr * (aNh[r] + bhh[2048 + jg]));
    size_t oh = (size_t)row * HID + jg;
    float hv = p2f(ldu16c(&chi[oh]), ldu16c(&clo[oh]));
    float val = (1.f - zz) * nn + zz * hv;
    out[(size_t)LSEQ * BATCH * LAT + oh] = val;        // output 1 (new_h)
    if (jg < LAT) {
      out[((size_t)t * BATCH + row) * LAT + jg] = val; // output 0
      u16 h, l; split2(val, h, l);
      stu16c(&nhi[oh], h); stu16c(&nhi[oh + LAT], h);
      stu16c(&nlo[oh], l); stu16c(&nlo[oh + LAT], l);
    }
  }
}

// ---------- one persistent kernel, 8 independent batch-row slices ----------
template<bool PLANES>
__global__ __launch_bounds__(256, 1) void fused_seq_k(
    const u16* __restrict__ w1h, const u16* __restrict__ w1l,
    const u16* __restrict__ w2h, const u16* __restrict__ w2l,
    const float* __restrict__ b1, const float* __restrict__ b2,
    u16* __restrict__ c0h, u16* __restrict__ c0l,
    u16* __restrict__ c1h, u16* __restrict__ c1l,
    u16* __restrict__ h1h, u16* __restrict__ h1l,
    const float* __restrict__ whh, const u16* __restrict__ whhh, const u16* __restrict__ whhl,
    const float* __restrict__ wih, const u16* __restrict__ wihh, const u16* __restrict__ wihl,
    const float* __restrict__ bih, const float* __restrict__ bhh,
    const float* __restrict__ data, float* __restrict__ out,
    unsigned* __restrict__ bar)
{
  __shared__ u16 pool[40960];   // 80 KB: gemm 8-slot / gru 4-slot staging
  const int b = blockIdx.x;
  const int tid = threadIdx.x;
  const int slice = b >> 5;
  const int l = b & 31;
  const int m0 = slice << 5;
  unsigned* line = bar + slice * 64;
  unsigned rnd = 0;

  u16* Sah = pool;              // 8 * 1280
  u16* Sal = pool + 10240;
  u16* Sbh = pool + 20480;
  u16* Sbl = pool + 30720;

  for (int t = 0; t < LSEQ; ++t) {
    u16* chi = (t & 1) ? c1h : c0h;
    u16* clo = (t & 1) ? c1l : c0l;
    u16* nhi = (t & 1) ? c0h : c1h;
    u16* nlo = (t & 1) ? c0l : c1l;
    for (int s = 0; s < 3; ++s) {
      {  // mlp1: h1 = tanh(y @ w1 + b1), K=512
        const int n0 = l << 5;
        gemm_phase<1, 16>(Sah, Sal, Sbh, Sbl,
                          chi, clo, HID, m0, w1h, w1l, 512, n0,
                          b1, h1h, h1l, data, t, tid);
      }
      ++rnd; slice_barrier(line, rnd);
      if (l < 16) {  // mlp2: y += (h1 @ w2 + b2)*dt/3, K=1024
        const int n0 = l << 5;
        gemm_phase<2, 32>(Sah, Sal, Sbh, Sbl,
                          h1h, h1l, HID, m0, w2h, w2l, 1024, n0,
                          b2, chi, clo, data, t, tid);
      }
      ++rnd; slice_barrier(line, rnd);
    }
    gru_phase<PLANES>(pool, chi, clo, whh, whhh, whhl, wih, wihh, wihl,
                      bih, bhh, data, t, nhi, nlo, out, l << 5, m0, tid);
    if (t + 1 < LSEQ) { ++rnd; slice_barrier(line, rnd); }
  }
}

extern "C" void kernel_launch(void* const* d_in, const int* in_sizes, int n_in,
                              void* d_out, int out_size, void* d_ws, size_t ws_size,
                              hipStream_t stream)
{
  const float* data = (const float*)d_in[0];
  const float* w1   = (const float*)d_in[1];
  const float* b1   = (const float*)d_in[2];
  const float* w2   = (const float*)d_in[3];
  const float* b2   = (const float*)d_in[4];
  const float* wih  = (const float*)d_in[5];
  const float* bih  = (const float*)d_in[6];
  const float* whh  = (const float*)d_in[7];
  const float* bhh  = (const float*)d_in[8];
  float* out = (float*)d_out;

  char* w = (char*)d_ws;
  auto alloc = [&](size_t bytes) { char* p = w; w += bytes; return p; };
  u16* w1h = (u16*)alloc((size_t)512 * 1024 * 2);   // [1024 n][512 k] planes
  u16* w1l = (u16*)alloc((size_t)512 * 1024 * 2);
  u16* w2h = (u16*)alloc((size_t)512 * 1024 * 2);   // [512 n][1024 k] planes
  u16* w2l = (u16*)alloc((size_t)512 * 1024 * 2);
  u16* c0h = (u16*)alloc((size_t)BATCH * HID * 2);
  u16* c0l = (u16*)alloc((size_t)BATCH * HID * 2);
  u16* c1h = (u16*)alloc((size_t)BATCH * HID * 2);
  u16* c1l = (u16*)alloc((size_t)BATCH * HID * 2);
  u16* h1h = (u16*)alloc((size_t)BATCH * HID * 2);
  u16* h1l = (u16*)alloc((size_t)BATCH * HID * 2);
  unsigned* bar = (unsigned*)alloc(4096);            // 16 counter lines, 256B apart
  size_t base = (size_t)(w - (char*)d_ws);
  size_t need_opt = base + 2 * ((size_t)3072 * 1024 * 2) + 2 * ((size_t)3072 * 256 * 2);
  bool planes = ws_size >= need_opt;
  u16 *whhh = nullptr, *whhl = nullptr, *wihh = nullptr, *wihl = nullptr;
  if (planes) {
    whhh = (u16*)alloc((size_t)3072 * 1024 * 2);
    whhl = (u16*)alloc((size_t)3072 * 1024 * 2);
    wihh = (u16*)alloc((size_t)3072 * 256 * 2);
    wihl = (u16*)alloc((size_t)3072 * 256 * 2);
  }

  tsplit_k<<<dim3(512 / 32, 1024 / 32), 256, 0, stream>>>(w1, w1h, w1l, 512, 1024);
  tsplit_k<<<dim3(1024 / 32, 512 / 32), 256, 0, stream>>>(w2, w2h, w2l, 1024, 512);
  if (planes) {
    esplit_k<<<dim3((3072 * 1024) / 1024), 256, 0, stream>>>(whh, whhh, whhl);
    esplit_k<<<dim3((3072 * 256) / 1024), 256, 0, stream>>>(wih, wihh, wihl);
  }
  init_k<<<dim3(256), 256, 0, stream>>>(c0h, c0l, bar);

  if (planes) {
    fused_seq_k<true><<<dim3(NBLK), dim3(256), 0, stream>>>(
        w1h, w1l, w2h, w2l, b1, b2, c0h, c0l, c1h, c1l, h1h, h1l,
        whh, whhh, whhl, wih, wihh, wihl, bih, bhh, data, out, bar);
  } else {
    fused_seq_k<false><<<dim3(NBLK), dim3(256), 0, stream>>>(
        w1h, w1l, w2h, w2l, b1, b2, c0h, c0l, c1h, c1l, h1h, h1l,
        whh, whhh, whhl, wih, wihh, wihl, bih, bhh, data, out, bar);
  }
}